// Round 3
// baseline (595.081 us; speedup 1.0000x reference)
//
#include <hip/hip_runtime.h>

typedef unsigned short u16;
typedef short short8 __attribute__((ext_vector_type(8)));
typedef float f32x4 __attribute__((ext_vector_type(4)));
typedef unsigned short u16x4 __attribute__((ext_vector_type(4)));

__device__ __forceinline__ u16 f2bf(float f) {
  unsigned u = __builtin_bit_cast(unsigned, f);
  u += 0x7fffu + ((u >> 16) & 1u);
  return (u16)(u >> 16);
}
__device__ __forceinline__ float bf2f(u16 s) {
  unsigned u = ((unsigned)s) << 16;
  return __builtin_bit_cast(float, u);
}
// packed f32x2 -> bf16x2 (lo = a, hi = b), RNE — gfx950 has no builtin (T12)
__device__ __forceinline__ unsigned cvtpk_bf16(float a, float b) {
  unsigned r;
  asm("v_cvt_pk_bf16_f32 %0, %1, %2" : "=v"(r) : "v"(a), "v"(b));
  return r;
}

#if __has_builtin(__builtin_amdgcn_exp2f)
#define EXP2F(x) __builtin_amdgcn_exp2f(x)
#else
#define EXP2F(x) exp2f(x)
#endif

#define MFMA32(a, b, c) __builtin_amdgcn_mfma_f32_16x16x32_bf16(a, b, c, 0, 0, 0)

#define GLDS16(gp, lp)                                                         \
  __builtin_amdgcn_global_load_lds(                                            \
      (__attribute__((address_space(1))) void*)(gp),                           \
      (__attribute__((address_space(3))) void*)(lp), 16, 0, 0)

// ---------------- cast fp32 -> bf16 ----------------
__global__ __launch_bounds__(256) void cast_bf16_k(const float* __restrict__ in,
                                                   u16* __restrict__ out, int n4) {
  int i = blockIdx.x * 256 + threadIdx.x;
  if (i >= n4) return;
  float4 v = ((const float4*)in)[i];
  u16x4 o = { f2bf(v.x), f2bf(v.y), f2bf(v.z), f2bf(v.w) };
  ((u16x4*)out)[i] = o;
}

// ---------------- weight transpose+cast: Wt[n][k] = W[k][n] ----------------
__global__ __launch_bounds__(256) void transw_k(const float* W0, const float* W1,
                                                const float* W2, const float* W3,
                                                const float* W4, const float* W5,
                                                u16* __restrict__ Wt) {
  int z = blockIdx.z;
  const float* W = z == 0 ? W0 : z == 1 ? W1 : z == 2 ? W2 : z == 3 ? W3 : z == 4 ? W4 : W5;
  u16* T = Wt + (size_t)z * 2048 * 2048;
  __shared__ float tile[64][65];
  int k0 = blockIdx.x * 64, n0 = blockIdx.y * 64;
  int c4 = (threadIdx.x & 15) * 4;
  int r = threadIdx.x >> 4;  // 0..15
#pragma unroll
  for (int i = 0; i < 4; ++i) {
    int row = r + i * 16;
    float4 v = *(const float4*)(W + (size_t)(k0 + row) * 2048 + n0 + c4);
    tile[row][c4 + 0] = v.x; tile[row][c4 + 1] = v.y;
    tile[row][c4 + 2] = v.z; tile[row][c4 + 3] = v.w;
  }
  __syncthreads();
#pragma unroll
  for (int i = 0; i < 4; ++i) {
    int nrow = r + i * 16;
    u16x4 o = { f2bf(tile[c4 + 0][nrow]), f2bf(tile[c4 + 1][nrow]),
                f2bf(tile[c4 + 2][nrow]), f2bf(tile[c4 + 3][nrow]) };
    *(u16x4*)(T + (size_t)(n0 + nrow) * 2048 + k0 + c4) = o;
  }
}

// ---------------- small-M GEMM (kept for K/V projections): out = A * Wt^T + bias ----------------
struct GemmJob {
  const u16* A; const u16* Bt; const float* bias; void* out;
  int M; int mode; int ldo;
};
struct GemmJobs { GemmJob j[8]; };

__global__ __launch_bounds__(256) void gemm_k(GemmJobs jobs) {
  GemmJob J = jobs.j[blockIdx.z];
  const int m0 = blockIdx.x * 128;
  if (m0 >= J.M) return;
  const int n0 = blockIdx.y * 128;
  __shared__ u16 Asm[128 * 32];
  __shared__ u16 Bsm[128 * 32];
  const int tid = threadIdx.x;
  const int lane = tid & 63;
  const int l15 = lane & 15, quad = lane >> 4;
  const int wave = tid >> 6;
  const int wr = (wave >> 1) * 64, wc = (wave & 1) * 64;
  f32x4 acc[4][4] = {};
  const int g0 = tid, g1 = tid + 256;
  const u16* ag0 = J.A + (size_t)(m0 + (g0 >> 2)) * 2048 + (g0 & 3) * 8;
  const u16* ag1 = J.A + (size_t)(m0 + (g1 >> 2)) * 2048 + (g1 & 3) * 8;
  const u16* bg0 = J.Bt + (size_t)(n0 + (g0 >> 2)) * 2048 + (g0 & 3) * 8;
  const u16* bg1 = J.Bt + (size_t)(n0 + (g1 >> 2)) * 2048 + (g1 & 3) * 8;
  u16* al0 = Asm + g0 * 8; u16* al1 = Asm + g1 * 8;
  u16* bl0 = Bsm + g0 * 8; u16* bl1 = Bsm + g1 * 8;
  for (int k0 = 0; k0 < 2048; k0 += 32) {
    GLDS16(ag0 + k0, al0);
    GLDS16(ag1 + k0, al1);
    GLDS16(bg0 + k0, bl0);
    GLDS16(bg1 + k0, bl1);
    __syncthreads();
    short8 af[4], bf[4];
#pragma unroll
    for (int mi = 0; mi < 4; ++mi)
      af[mi] = *(const short8*)(Asm + (wr + mi * 16 + l15) * 32 + quad * 8);
#pragma unroll
    for (int ni = 0; ni < 4; ++ni)
      bf[ni] = *(const short8*)(Bsm + (wc + ni * 16 + l15) * 32 + quad * 8);
#pragma unroll
    for (int mi = 0; mi < 4; ++mi)
#pragma unroll
      for (int ni = 0; ni < 4; ++ni)
        acc[mi][ni] = __builtin_amdgcn_mfma_f32_16x16x32_bf16(af[mi], bf[ni], acc[mi][ni], 0, 0, 0);
    __syncthreads();
  }
#pragma unroll
  for (int mi = 0; mi < 4; ++mi) {
#pragma unroll
    for (int ni = 0; ni < 4; ++ni) {
      int nn = n0 + wc + ni * 16 + l15;
      float bv = J.bias[nn];
#pragma unroll
      for (int r = 0; r < 4; ++r) {
        int mm = m0 + wr + mi * 16 + quad * 4 + r;
        if (mm >= J.M) continue;
        float v = acc[mi][ni][r] + bv;
        if (J.mode == 0) {
          ((u16*)J.out)[(size_t)mm * J.ldo + nn] = f2bf(v);
        } else if (J.mode == 1) {
          int ml = mm & 31;
          int mp = (mm & ~31) | (((ml >> 2) & 3) * 8 + (ml >> 4) * 4 + (ml & 3));
          ((u16*)J.out)[(size_t)nn * J.ldo + mp] = f2bf(v);
        } else {
          ((float*)J.out)[(size_t)mm * J.ldo + nn] = v;
        }
      }
    }
  }
}

// ---------------- big GEMM: 256x256 tile, BK=32, prefetch-lead pipeline ----------------
__global__ __launch_bounds__(512, 2) void gemm256_k(const u16* __restrict__ A,
                                                    const u16* __restrict__ Bt,
                                                    const float* __restrict__ bias,
                                                    void* __restrict__ out,
                                                    int mode) {
  const int m0 = blockIdx.x * 256, n0 = blockIdx.y * 256;
  __shared__ u16 lds[2][2][256 * 32];  // [buf][A,B][row*32 + col], 64 KiB total
  const int tid = threadIdx.x, lane = tid & 63;
  const int l15 = lane & 15, quad = lane >> 4;
  const int wave = tid >> 6;
  const int wr = wave >> 2;   // 0..1 : M half (128 rows)
  const int wc = wave & 3;    // 0..3 : N quarter (64 cols)
  const int srow = tid >> 2;                       // 0..127
  const int sc = ((tid & 3) ^ ((srow >> 1) & 3)) * 8;  // pre-swizzled source col
  const u16* Ag = A + (size_t)(m0 + srow) * 2048 + sc;
  const u16* Bg = Bt + (size_t)(n0 + srow) * 2048 + sc;
  const int lxor = (l15 >> 1) & 3;                 // read-side swizzle
  f32x4 acc[8][4] = {};

  auto stage = [&](int buf, int kt) {
    const size_t ko = (size_t)kt * 32;
    u16* dA = &lds[buf][0][tid * 8];
    u16* dB = &lds[buf][1][tid * 8];
    GLDS16(Ag + ko, dA);
    GLDS16(Ag + (size_t)128 * 2048 + ko, dA + 4096);
    GLDS16(Bg + ko, dB);
    GLDS16(Bg + (size_t)128 * 2048 + ko, dB + 4096);
  };

  stage(0, 0);
  for (int t = 0; t < 64; ++t) {
    const int cb = t & 1;
    __syncthreads();  // drains tile t's loads (issued a full tile ago)
    if (t + 1 < 64) stage(cb ^ 1, t + 1);
    const u16* Ab = &lds[cb][0][(size_t)wr * 128 * 32];
    const u16* Bb = &lds[cb][1][0];
    short8 bfr[4];
#pragma unroll
    for (int ni = 0; ni < 4; ++ni) {
      const int rn = wc * 64 + ni * 16 + l15;
      bfr[ni] = *(const short8*)(Bb + rn * 32 + ((quad ^ lxor) * 8));
    }
#pragma unroll
    for (int mi = 0; mi < 8; ++mi) {
      const int rm = mi * 16 + l15;
      short8 a = *(const short8*)(Ab + rm * 32 + ((quad ^ lxor) * 8));
      __builtin_amdgcn_s_setprio(1);
#pragma unroll
      for (int ni = 0; ni < 4; ++ni)
        acc[mi][ni] = MFMA32(a, bfr[ni], acc[mi][ni]);
      __builtin_amdgcn_s_setprio(0);
    }
  }
#pragma unroll
  for (int mi = 0; mi < 8; ++mi) {
#pragma unroll
    for (int ni = 0; ni < 4; ++ni) {
      const int nn = n0 + wc * 64 + ni * 16 + l15;
      const float bv = bias[nn];
      const int mm = m0 + wr * 128 + mi * 16 + quad * 4;
      if (mode == 0) {
        u16* op = (u16*)out + (size_t)mm * 2048 + nn;
#pragma unroll
        for (int r = 0; r < 4; ++r) op[(size_t)r * 2048] = f2bf(acc[mi][ni][r] + bv);
      } else {
        float* op = (float*)out + (size_t)mm * 2048 + nn;
#pragma unroll
        for (int r = 0; r < 4; ++r) op[(size_t)r * 2048] = acc[mi][ni][r] + bv;
      }
    }
  }
}

// ---------------- RMSNorm in place (rows of 2048 bf16) ----------------
__global__ __launch_bounds__(256) void rmsnorm_k(u16* __restrict__ buf,
                                                 const float* __restrict__ g) {
  const int row = blockIdx.x, tid = threadIdx.x;
  u16* p = buf + (size_t)row * 2048 + tid * 8;
  short8 v = *(short8*)p;
  float x[8]; float s = 0.f;
#pragma unroll
  for (int i = 0; i < 8; ++i) { x[i] = bf2f((u16)v[i]); s += x[i] * x[i]; }
#pragma unroll
  for (int o = 1; o < 64; o <<= 1) s += __shfl_xor(s, o, 64);
  __shared__ float ws4[4];
  if ((tid & 63) == 0) ws4[tid >> 6] = s;
  __syncthreads();
  float tot = ws4[0] + ws4[1] + ws4[2] + ws4[3];
  float scale = rsqrtf(tot * (1.0f / 2048.0f) + 1e-6f);
  const float* gp = g + tid * 8;
  short8 o8;
#pragma unroll
  for (int i = 0; i < 8; ++i) o8[i] = (short)f2bf(x[i] * scale * gp[i]);
  *(short8*)p = o8;
}

// ---------------- flash attention ----------------
// R3: T4 counted-vmcnt pipeline. 3 LDS buffers, depth-2 prefetch: tile t's
// loads were issued at iter t-2 (~2 compute phases + 2 barriers of cover).
// Per tile: s_waitcnt vmcnt(4) (waits ONLY tile t's 4 loads; t+1's stay in
// flight) -> raw s_barrier -> stage tile t+2 -> compute. Stage-after-barrier
// makes the 3-buffer rotation race-free: all waves passed the barrier =>
// finished reading buf[(t+2)%3] (last read at tile t-1). Always-issue-4
// (clamped dummy tiles, never read) keeps the vmcnt count exact; vmcnt(4)
// can only over-wait (oldest-first), never under-wait.
// XCD swizzle: 1024 blocks = 8 XCDs x 128; each XCD gets 4 (b,h) pairs x
// all 32 q-tiles so the shared K/V slice (~390 KB) is fetched once per XCD
// and served from its local L2.
__global__ __launch_bounds__(256) void attn_k(const u16* __restrict__ Q,
                                              const u16* __restrict__ Kt,
                                              const u16* __restrict__ Vt,
                                              const u16* __restrict__ Ki,
                                              const u16* __restrict__ Vi,
                                              const int* __restrict__ lens,
                                              u16* __restrict__ out) {
  // bijective XCD swizzle of the 32x16x2 grid
  const int lid = blockIdx.x + 32 * (blockIdx.y + 16 * blockIdx.z);
  const int w = (lid & 7) * 128 + (lid >> 3);
  const int qx = w & 31, hb = w >> 5;
  const int h = hb & 15, b = hb >> 4;

  const int tid = threadIdx.x, lane = tid & 63, wave = tid >> 6;
  const int l15 = lane & 15, quad = lane >> 4;
  const int qbase = qx * 128 + wave * 32;
  const float scale2 = 0.12752358514837517f;  // (1/sqrt(128)) * log2(e)
  const float NEGINF = -__builtin_inff();
  __shared__ u16 Ksm[3][32 * 128];  // K rows x d, 16B chunks XOR-swizzled: cc' = cc ^ (row&7)
  __shared__ u16 Vsm[3][128 * 32];  // d rows x 32 permuted key cols, chunk' = chunk ^ ((row>>1)&3)

  short8 qf[2][4];
#pragma unroll
  for (int h2 = 0; h2 < 2; ++h2) {
    const u16* qb = Q + ((size_t)(b * 4096 + qbase + h2 * 16 + l15)) * 2048 + h * 128 + quad * 8;
#pragma unroll
    for (int kc = 0; kc < 4; ++kc) qf[h2][kc] = *(const short8*)(qb + kc * 32);
  }

  const int krow = tid >> 4;
  const int kcc = ((tid & 15) ^ (krow & 7)) * 8;
  const int vd = tid >> 2;
  const int vcs = ((tid & 3) ^ ((tid >> 3) & 3)) * 8;
  const int kxor = l15 & 7;
  const int vxor = (l15 >> 1) & 3;

  f32x4 accv[2][8];
  u16x4 oimg[2][8];
  float run_m[2], run_l[2];

  auto phase = [&](const u16* Kb, const u16* Vb, int Lv, int ldv) {
    run_m[0] = run_m[1] = NEGINF;
    run_l[0] = run_l[1] = 0.f;
#pragma unroll
    for (int h2 = 0; h2 < 2; ++h2)
#pragma unroll
      for (int dt = 0; dt < 8; ++dt)
#pragma unroll
        for (int r = 0; r < 4; ++r) accv[h2][dt][r] = 0.f;
    const u16* kg0 = Kb + (size_t)krow * 2048 + kcc;
    const u16* kg1 = kg0 + 16 * 2048;
    const u16* vg0 = Vb + (size_t)vd * ldv + vcs;
    const u16* vg1 = vg0 + (size_t)64 * ldv;
    const int ntiles = (Lv + 31) >> 5;
    // guard cross-phase LDS buffer reuse (prev phase's readers must finish)
    __builtin_amdgcn_s_barrier();
    // prologue: stage tiles 0 and 1 (clamped) into buffers 0,1
    {
      GLDS16(kg0, &Ksm[0][tid * 8]);
      GLDS16(kg1, &Ksm[0][2048 + tid * 8]);
      GLDS16(vg0, &Vsm[0][tid * 8]);
      GLDS16(vg1, &Vsm[0][2048 + tid * 8]);
      const size_t k1 = (ntiles > 1) ? 32 : 0;
      GLDS16(kg0 + k1 * 2048, &Ksm[1][tid * 8]);
      GLDS16(kg1 + k1 * 2048, &Ksm[1][2048 + tid * 8]);
      GLDS16(vg0 + k1, &Vsm[1][tid * 8]);
      GLDS16(vg1 + k1, &Vsm[1][2048 + tid * 8]);
    }
    int cb = 0, nb = 2;  // current buffer, stage-target buffer = (t+2)%3
    for (int t = 0; t < ntiles; ++t) {
      // wait for tile t's 4 loads (oldest); tiles t+1 (and later t+2) stay in flight
      asm volatile("s_waitcnt vmcnt(4)" ::: "memory");
      __builtin_amdgcn_s_barrier();
      // stage tile t+2 (clamped dummy if past end) into buf nb
      {
        const size_t kn = (size_t)((t + 2 < ntiles) ? (t + 2) * 32 : 0);
        GLDS16(kg0 + kn * 2048, &Ksm[nb][tid * 8]);
        GLDS16(kg1 + kn * 2048, &Ksm[nb][2048 + tid * 8]);
        GLDS16(vg0 + kn, &Vsm[nb][tid * 8]);
        GLDS16(vg1 + kn, &Vsm[nb][2048 + tid * 8]);
      }
      const u16* Ks = Ksm[cb];
      const u16* Vs = Vsm[cb];

      short8 kf0[4], kf1[4];
#pragma unroll
      for (int kc = 0; kc < 4; ++kc) {
        int c0 = ((kc * 4 + quad) ^ kxor) * 8;
        kf0[kc] = *(const short8*)(Ks + l15 * 128 + c0);
        kf1[kc] = *(const short8*)(Ks + (16 + l15) * 128 + c0);
      }
      f32x4 s0[2], s1[2];
#pragma unroll
      for (int h2 = 0; h2 < 2; ++h2)
#pragma unroll
        for (int r = 0; r < 4; ++r) { s0[h2][r] = 0.f; s1[h2][r] = 0.f; }
      __builtin_amdgcn_s_setprio(1);
#pragma unroll
      for (int h2 = 0; h2 < 2; ++h2)
#pragma unroll
        for (int kc = 0; kc < 4; ++kc) {
          s0[h2] = MFMA32(kf0[kc], qf[h2][kc], s0[h2]);
          s1[h2] = MFMA32(kf1[kc], qf[h2][kc], s1[h2]);
        }
      __builtin_amdgcn_s_setprio(0);
      const int kv0 = t * 32;
      if (kv0 + 32 > Lv) {
#pragma unroll
        for (int h2 = 0; h2 < 2; ++h2)
#pragma unroll
          for (int r = 0; r < 4; ++r) {
            const int k0i = kv0 + quad * 4 + r;
            if (k0i >= Lv) s0[h2][r] = NEGINF;
            if (k0i + 16 >= Lv) s1[h2][r] = NEGINF;
          }
      }
      float al[2];
      short8 pf[2];
#pragma unroll
      for (int h2 = 0; h2 < 2; ++h2) {
        float mx = fmaxf(fmaxf(fmaxf(s0[h2][0], s0[h2][1]), fmaxf(s0[h2][2], s0[h2][3])),
                         fmaxf(fmaxf(s1[h2][0], s1[h2][1]), fmaxf(s1[h2][2], s1[h2][3])));
        mx = fmaxf(mx, __shfl_xor(mx, 16, 64));
        mx = fmaxf(mx, __shfl_xor(mx, 32, 64));
        const float nm = fmaxf(run_m[h2], mx);
        al[h2] = EXP2F((run_m[h2] - nm) * scale2);
        run_m[h2] = nm;
        const float nmc = -nm * scale2;
        float p0[4], p1[4], psum = 0.f;
#pragma unroll
        for (int r = 0; r < 4; ++r) {
          p0[r] = EXP2F(__builtin_fmaf(s0[h2][r], scale2, nmc));
          p1[r] = EXP2F(__builtin_fmaf(s1[h2][r], scale2, nmc));
          psum += p0[r] + p1[r];
        }
        run_l[h2] = __builtin_fmaf(run_l[h2], al[h2], psum);
        union { short8 s8; unsigned u[4]; } pp;
        pp.u[0] = cvtpk_bf16(p0[0], p0[1]);
        pp.u[1] = cvtpk_bf16(p0[2], p0[3]);
        pp.u[2] = cvtpk_bf16(p1[0], p1[1]);
        pp.u[3] = cvtpk_bf16(p1[2], p1[3]);
        pf[h2] = pp.s8;
      }
      if (t != 0 && __ballot((al[0] < 1.0f) || (al[1] < 1.0f))) {
#pragma unroll
        for (int h2 = 0; h2 < 2; ++h2)
#pragma unroll
          for (int dt = 0; dt < 8; ++dt)
#pragma unroll
            for (int r = 0; r < 4; ++r) accv[h2][dt][r] *= al[h2];
      }
      __builtin_amdgcn_s_setprio(1);
#pragma unroll
      for (int dt = 0; dt < 8; ++dt) {
        short8 vf = *(const short8*)(Vs + (dt * 16 + l15) * 32 + ((quad ^ vxor) * 8));
        accv[0][dt] = MFMA32(vf, pf[0], accv[0][dt]);
        accv[1][dt] = MFMA32(vf, pf[1], accv[1][dt]);
      }
      __builtin_amdgcn_s_setprio(0);
      cb = (cb == 2) ? 0 : cb + 1;
      nb = (nb == 2) ? 0 : nb + 1;
    }
  };

  const u16* Kb_i = Ki + (size_t)(b * 288) * 2048 + h * 128;
  const u16* Vb_i = Vi + ((size_t)(b * 16 + h) * 128) * 288;
  phase(Kb_i, Vb_i, 257, 288);
#pragma unroll
  for (int h2 = 0; h2 < 2; ++h2) {
    float a = run_l[h2] + __shfl_xor(run_l[h2], 16, 64);
    float lt = a + __shfl_xor(a, 32, 64);
    float inv = 1.0f / lt;
#pragma unroll
    for (int dt = 0; dt < 8; ++dt) {
      u16x4 w2 = { f2bf(accv[h2][dt][0] * inv), f2bf(accv[h2][dt][1] * inv),
                   f2bf(accv[h2][dt][2] * inv), f2bf(accv[h2][dt][3] * inv) };
      oimg[h2][dt] = w2;
    }
  }
  const u16* Kb_t = Kt + (size_t)(b * 512) * 2048 + h * 128;
  const u16* Vb_t = Vt + ((size_t)(b * 16 + h) * 128) * 512;
  phase(Kb_t, Vb_t, lens[b], 512);
#pragma unroll
  for (int h2 = 0; h2 < 2; ++h2) {
    float a = run_l[h2] + __shfl_xor(run_l[h2], 16, 64);
    float lt = a + __shfl_xor(a, 32, 64);
    float inv = 1.0f / lt;
    u16* ob = out + ((size_t)(b * 4096 + qbase + h2 * 16 + l15)) * 2048 + h * 128 + quad * 4;
#pragma unroll
    for (int dt = 0; dt < 8; ++dt) {
      u16x4 w2 = { f2bf(bf2f(oimg[h2][dt][0]) + accv[h2][dt][0] * inv),
                   f2bf(bf2f(oimg[h2][dt][1]) + accv[h2][dt][1] * inv),
                   f2bf(bf2f(oimg[h2][dt][2]) + accv[h2][dt][2] * inv),
                   f2bf(bf2f(oimg[h2][dt][3]) + accv[h2][dt][3] * inv) };
      *(u16x4*)(ob + dt * 16) = w2;
    }
  }
}

extern "C" void kernel_launch(void* const* d_in, const int* in_sizes, int n_in,
                              void* d_out, int out_size, void* d_ws, size_t ws_size,
                              hipStream_t stream) {
  const float* x   = (const float*)d_in[0];
  const float* ctx = (const float*)d_in[1];
  const int* lens  = (const int*)d_in[2];
  const float* Wq  = (const float*)d_in[3];
  const float* bq  = (const float*)d_in[4];
  const float* gq  = (const float*)d_in[5];
  const float* Wk  = (const float*)d_in[6];
  const float* bk  = (const float*)d_in[7];
  const float* gk  = (const float*)d_in[8];
  const float* Wv  = (const float*)d_in[9];
  const float* bv  = (const float*)d_in[10];
  const float* Wki = (const float*)d_in[11];
  const float* bki = (const float*)d_in[12];
  const float* gki = (const float*)d_in[13];
  const float* Wvi = (const float*)d_in[14];
  const float* bvi = (const float*)d_in[15];
  const float* Wo  = (const float*)d_in[16];
  const float* bo  = (const float*)d_in[17];
  float* out = (float*)d_out;

  char* p = (char*)d_ws;
  u16* x_bf   = (u16*)p; p += (size_t)8192 * 2048 * 2;     // reused as attn_out
  u16* ctx_bf = (u16*)p; p += (size_t)2 * 769 * 2048 * 2;
  u16* Wt     = (u16*)p; p += (size_t)6 * 2048 * 2048 * 2;
  u16* Qb     = (u16*)p; p += (size_t)8192 * 2048 * 2;
  u16* Ktxt   = (u16*)p; p += (size_t)2 * 512 * 2048 * 2;
  u16* Vtt    = (u16*)p; p += (size_t)2 * 16 * 128 * 512 * 2;
  u16* Kimg   = (u16*)p; p += (size_t)2 * 288 * 2048 * 2;
  u16* Vti    = (u16*)p; p += (size_t)2 * 16 * 128 * 288 * 2;
  u16* attn_o = x_bf;

  cast_bf16_k<<<16384, 256, 0, stream>>>(x, x_bf, 8192 * 2048 / 4);
  cast_bf16_k<<<3076, 256, 0, stream>>>(ctx, ctx_bf, 2 * 769 * 2048 / 4);
  transw_k<<<dim3(32, 32, 6), 256, 0, stream>>>(Wq, Wk, Wv, Wki, Wvi, Wo, Wt);

  // Q projection: 8192x2048x2048 -> bf16
  gemm256_k<<<dim3(32, 8), 512, 0, stream>>>(x_bf, Wt + 0ull * 4194304, bq, Qb, 0);

  GemmJobs jc = {};
  for (int b = 0; b < 2; ++b) {
    const u16* txtA = ctx_bf + (size_t)(b * 769 + 257) * 2048;
    const u16* imgA = ctx_bf + (size_t)(b * 769) * 2048;
    jc.j[0 + b] = { txtA, Wt + 1ull * 4194304, bk,  Ktxt + (size_t)b * 512 * 2048, 512, 0, 2048 };
    jc.j[2 + b] = { txtA, Wt + 2ull * 4194304, bv,  Vtt  + (size_t)b * 2048 * 512, 512, 1, 512 };
    jc.j[4 + b] = { imgA, Wt + 3ull * 4194304, bki, Kimg + (size_t)b * 288 * 2048, 257, 0, 2048 };
    jc.j[6 + b] = { imgA, Wt + 4ull * 4194304, bvi, Vti  + (size_t)b * 2048 * 288, 257, 1, 288 };
  }
  gemm_k<<<dim3(4, 16, 8), 256, 0, stream>>>(jc);

  rmsnorm_k<<<8192, 256, 0, stream>>>(Qb, gq);
  rmsnorm_k<<<1024, 256, 0, stream>>>(Ktxt, gk);
  rmsnorm_k<<<576, 256, 0, stream>>>(Kimg, gki);

  attn_k<<<dim3(32, 16, 2), 256, 0, stream>>>(Qb, Ktxt, Vtt, Kimg, Vti, lens, attn_o);

  // output projection: 8192x2048x2048 -> fp32
  gemm256_k<<<dim3(32, 8), 512, 0, stream>>>(attn_o, Wt + 5ull * 4194304, bo, out, 1);
}

// Round 4
// 514.944 us; speedup vs baseline: 1.1556x; 1.1556x over previous
//
#include <hip/hip_runtime.h>

typedef unsigned short u16;
typedef short short8 __attribute__((ext_vector_type(8)));
typedef float f32x4 __attribute__((ext_vector_type(4)));
typedef unsigned short u16x4 __attribute__((ext_vector_type(4)));

__device__ __forceinline__ u16 f2bf(float f) {
  unsigned u = __builtin_bit_cast(unsigned, f);
  u += 0x7fffu + ((u >> 16) & 1u);
  return (u16)(u >> 16);
}
__device__ __forceinline__ float bf2f(u16 s) {
  unsigned u = ((unsigned)s) << 16;
  return __builtin_bit_cast(float, u);
}
// packed f32x2 -> bf16x2 (lo = a, hi = b), RNE — gfx950 has no builtin (T12)
__device__ __forceinline__ unsigned cvtpk_bf16(float a, float b) {
  unsigned r;
  asm("v_cvt_pk_bf16_f32 %0, %1, %2" : "=v"(r) : "v"(a), "v"(b));
  return r;
}

#if __has_builtin(__builtin_amdgcn_exp2f)
#define EXP2F(x) __builtin_amdgcn_exp2f(x)
#else
#define EXP2F(x) exp2f(x)
#endif

#define MFMA32(a, b, c) __builtin_amdgcn_mfma_f32_16x16x32_bf16(a, b, c, 0, 0, 0)

#define GLDS16(gp, lp)                                                         \
  __builtin_amdgcn_global_load_lds(                                            \
      (__attribute__((address_space(1))) void*)(gp),                           \
      (__attribute__((address_space(3))) void*)(lp), 16, 0, 0)

// ---------------- cast fp32 -> bf16 ----------------
__global__ __launch_bounds__(256) void cast_bf16_k(const float* __restrict__ in,
                                                   u16* __restrict__ out, int n4) {
  int i = blockIdx.x * 256 + threadIdx.x;
  if (i >= n4) return;
  float4 v = ((const float4*)in)[i];
  u16x4 o = { f2bf(v.x), f2bf(v.y), f2bf(v.z), f2bf(v.w) };
  ((u16x4*)out)[i] = o;
}

// ---------------- weight transpose+cast: Wt[n][k] = W[k][n] ----------------
__global__ __launch_bounds__(256) void transw_k(const float* W0, const float* W1,
                                                const float* W2, const float* W3,
                                                const float* W4, const float* W5,
                                                u16* __restrict__ Wt) {
  int z = blockIdx.z;
  const float* W = z == 0 ? W0 : z == 1 ? W1 : z == 2 ? W2 : z == 3 ? W3 : z == 4 ? W4 : W5;
  u16* T = Wt + (size_t)z * 2048 * 2048;
  __shared__ float tile[64][65];
  int k0 = blockIdx.x * 64, n0 = blockIdx.y * 64;
  int c4 = (threadIdx.x & 15) * 4;
  int r = threadIdx.x >> 4;  // 0..15
#pragma unroll
  for (int i = 0; i < 4; ++i) {
    int row = r + i * 16;
    float4 v = *(const float4*)(W + (size_t)(k0 + row) * 2048 + n0 + c4);
    tile[row][c4 + 0] = v.x; tile[row][c4 + 1] = v.y;
    tile[row][c4 + 2] = v.z; tile[row][c4 + 3] = v.w;
  }
  __syncthreads();
#pragma unroll
  for (int i = 0; i < 4; ++i) {
    int nrow = r + i * 16;
    u16x4 o = { f2bf(tile[c4 + 0][nrow]), f2bf(tile[c4 + 1][nrow]),
                f2bf(tile[c4 + 2][nrow]), f2bf(tile[c4 + 3][nrow]) };
    *(u16x4*)(T + (size_t)(n0 + nrow) * 2048 + k0 + c4) = o;
  }
}

// ---------------- small-M GEMM (kept for K/V projections): out = A * Wt^T + bias ----------------
struct GemmJob {
  const u16* A; const u16* Bt; const float* bias; void* out;
  int M; int mode; int ldo;
};
struct GemmJobs { GemmJob j[8]; };

__global__ __launch_bounds__(256) void gemm_k(GemmJobs jobs) {
  GemmJob J = jobs.j[blockIdx.z];
  const int m0 = blockIdx.x * 128;
  if (m0 >= J.M) return;
  const int n0 = blockIdx.y * 128;
  __shared__ u16 Asm[128 * 32];
  __shared__ u16 Bsm[128 * 32];
  const int tid = threadIdx.x;
  const int lane = tid & 63;
  const int l15 = lane & 15, quad = lane >> 4;
  const int wave = tid >> 6;
  const int wr = (wave >> 1) * 64, wc = (wave & 1) * 64;
  f32x4 acc[4][4] = {};
  const int g0 = tid, g1 = tid + 256;
  const u16* ag0 = J.A + (size_t)(m0 + (g0 >> 2)) * 2048 + (g0 & 3) * 8;
  const u16* ag1 = J.A + (size_t)(m0 + (g1 >> 2)) * 2048 + (g1 & 3) * 8;
  const u16* bg0 = J.Bt + (size_t)(n0 + (g0 >> 2)) * 2048 + (g0 & 3) * 8;
  const u16* bg1 = J.Bt + (size_t)(n0 + (g1 >> 2)) * 2048 + (g1 & 3) * 8;
  u16* al0 = Asm + g0 * 8; u16* al1 = Asm + g1 * 8;
  u16* bl0 = Bsm + g0 * 8; u16* bl1 = Bsm + g1 * 8;
  for (int k0 = 0; k0 < 2048; k0 += 32) {
    GLDS16(ag0 + k0, al0);
    GLDS16(ag1 + k0, al1);
    GLDS16(bg0 + k0, bl0);
    GLDS16(bg1 + k0, bl1);
    __syncthreads();
    short8 af[4], bf[4];
#pragma unroll
    for (int mi = 0; mi < 4; ++mi)
      af[mi] = *(const short8*)(Asm + (wr + mi * 16 + l15) * 32 + quad * 8);
#pragma unroll
    for (int ni = 0; ni < 4; ++ni)
      bf[ni] = *(const short8*)(Bsm + (wc + ni * 16 + l15) * 32 + quad * 8);
#pragma unroll
    for (int mi = 0; mi < 4; ++mi)
#pragma unroll
      for (int ni = 0; ni < 4; ++ni)
        acc[mi][ni] = __builtin_amdgcn_mfma_f32_16x16x32_bf16(af[mi], bf[ni], acc[mi][ni], 0, 0, 0);
    __syncthreads();
  }
#pragma unroll
  for (int mi = 0; mi < 4; ++mi) {
#pragma unroll
    for (int ni = 0; ni < 4; ++ni) {
      int nn = n0 + wc + ni * 16 + l15;
      float bv = J.bias[nn];
#pragma unroll
      for (int r = 0; r < 4; ++r) {
        int mm = m0 + wr + mi * 16 + quad * 4 + r;
        if (mm >= J.M) continue;
        float v = acc[mi][ni][r] + bv;
        if (J.mode == 0) {
          ((u16*)J.out)[(size_t)mm * J.ldo + nn] = f2bf(v);
        } else if (J.mode == 1) {
          int ml = mm & 31;
          int mp = (mm & ~31) | (((ml >> 2) & 3) * 8 + (ml >> 4) * 4 + (ml & 3));
          ((u16*)J.out)[(size_t)nn * J.ldo + mp] = f2bf(v);
        } else {
          ((float*)J.out)[(size_t)mm * J.ldo + nn] = v;
        }
      }
    }
  }
}

// ---------------- big GEMM: 256x256 tile, BK=32, prefetch-lead pipeline ----------------
__global__ __launch_bounds__(512, 2) void gemm256_k(const u16* __restrict__ A,
                                                    const u16* __restrict__ Bt,
                                                    const float* __restrict__ bias,
                                                    void* __restrict__ out,
                                                    int mode) {
  const int m0 = blockIdx.x * 256, n0 = blockIdx.y * 256;
  __shared__ u16 lds[2][2][256 * 32];  // [buf][A,B][row*32 + col], 64 KiB total
  const int tid = threadIdx.x, lane = tid & 63;
  const int l15 = lane & 15, quad = lane >> 4;
  const int wave = tid >> 6;
  const int wr = wave >> 2;   // 0..1 : M half (128 rows)
  const int wc = wave & 3;    // 0..3 : N quarter (64 cols)
  const int srow = tid >> 2;                       // 0..127
  const int sc = ((tid & 3) ^ ((srow >> 1) & 3)) * 8;  // pre-swizzled source col
  const u16* Ag = A + (size_t)(m0 + srow) * 2048 + sc;
  const u16* Bg = Bt + (size_t)(n0 + srow) * 2048 + sc;
  const int lxor = (l15 >> 1) & 3;                 // read-side swizzle
  f32x4 acc[8][4] = {};

  auto stage = [&](int buf, int kt) {
    const size_t ko = (size_t)kt * 32;
    u16* dA = &lds[buf][0][tid * 8];
    u16* dB = &lds[buf][1][tid * 8];
    GLDS16(Ag + ko, dA);
    GLDS16(Ag + (size_t)128 * 2048 + ko, dA + 4096);
    GLDS16(Bg + ko, dB);
    GLDS16(Bg + (size_t)128 * 2048 + ko, dB + 4096);
  };

  stage(0, 0);
  for (int t = 0; t < 64; ++t) {
    const int cb = t & 1;
    __syncthreads();  // drains tile t's loads (issued a full tile ago)
    if (t + 1 < 64) stage(cb ^ 1, t + 1);
    const u16* Ab = &lds[cb][0][(size_t)wr * 128 * 32];
    const u16* Bb = &lds[cb][1][0];
    short8 bfr[4];
#pragma unroll
    for (int ni = 0; ni < 4; ++ni) {
      const int rn = wc * 64 + ni * 16 + l15;
      bfr[ni] = *(const short8*)(Bb + rn * 32 + ((quad ^ lxor) * 8));
    }
#pragma unroll
    for (int mi = 0; mi < 8; ++mi) {
      const int rm = mi * 16 + l15;
      short8 a = *(const short8*)(Ab + rm * 32 + ((quad ^ lxor) * 8));
      __builtin_amdgcn_s_setprio(1);
#pragma unroll
      for (int ni = 0; ni < 4; ++ni)
        acc[mi][ni] = MFMA32(a, bfr[ni], acc[mi][ni]);
      __builtin_amdgcn_s_setprio(0);
    }
  }
#pragma unroll
  for (int mi = 0; mi < 8; ++mi) {
#pragma unroll
    for (int ni = 0; ni < 4; ++ni) {
      const int nn = n0 + wc * 64 + ni * 16 + l15;
      const float bv = bias[nn];
      const int mm = m0 + wr * 128 + mi * 16 + quad * 4;
      if (mode == 0) {
        u16* op = (u16*)out + (size_t)mm * 2048 + nn;
#pragma unroll
        for (int r = 0; r < 4; ++r) op[(size_t)r * 2048] = f2bf(acc[mi][ni][r] + bv);
      } else {
        float* op = (float*)out + (size_t)mm * 2048 + nn;
#pragma unroll
        for (int r = 0; r < 4; ++r) op[(size_t)r * 2048] = acc[mi][ni][r] + bv;
      }
    }
  }
}

// ---------------- RMSNorm in place (rows of 2048 bf16) ----------------
__global__ __launch_bounds__(256) void rmsnorm_k(u16* __restrict__ buf,
                                                 const float* __restrict__ g) {
  const int row = blockIdx.x, tid = threadIdx.x;
  u16* p = buf + (size_t)row * 2048 + tid * 8;
  short8 v = *(short8*)p;
  float x[8]; float s = 0.f;
#pragma unroll
  for (int i = 0; i < 8; ++i) { x[i] = bf2f((u16)v[i]); s += x[i] * x[i]; }
#pragma unroll
  for (int o = 1; o < 64; o <<= 1) s += __shfl_xor(s, o, 64);
  __shared__ float ws4[4];
  if ((tid & 63) == 0) ws4[tid >> 6] = s;
  __syncthreads();
  float tot = ws4[0] + ws4[1] + ws4[2] + ws4[3];
  float scale = rsqrtf(tot * (1.0f / 2048.0f) + 1e-6f);
  const float* gp = g + tid * 8;
  short8 o8;
#pragma unroll
  for (int i = 0; i < 8; ++i) o8[i] = (short)f2bf(x[i] * scale * gp[i]);
  *(short8*)p = o8;
}

// ---------------- flash attention ----------------
// R4: KVBLK=64 (two proven 32-key sub-tiles per step), 8-wave/512-thread
// blocks, 256 q-rows/block. One softmax pass + one barrier pair + one
// stage per 64 keys — halves the per-key serial overhead that R0-R3
// showed to be invariant under memory-side fixes. Pipeline = R1's
// best-measured stage-ahead-1 (__syncthreads drain lands after a full
// 64-key compute phase). K sub-tile [32][128] cc^=(row&7); V^T sub-tile
// [128][32] chunk^=((row>>1)&3) — both swizzles carried over unchanged.
// Tail: staging SOURCE clamped in-bounds (img keys 288..319 don't exist);
// score masking guarantees P=0 for clamped/dummy keys.
__global__ __launch_bounds__(512) void attn_k(const u16* __restrict__ Q,
                                              const u16* __restrict__ Kt,
                                              const u16* __restrict__ Vt,
                                              const u16* __restrict__ Ki,
                                              const u16* __restrict__ Vi,
                                              const int* __restrict__ lens,
                                              u16* __restrict__ out) {
  // bijective XCD swizzle of the 16x16x2 grid (512 = 8 XCDs x 64)
  const int lid = blockIdx.x + 16 * (blockIdx.y + 16 * blockIdx.z);
  const int w = (lid & 7) * 64 + (lid >> 3);
  const int qx = w & 15, hb = w >> 4;
  const int h = hb & 15, b = hb >> 4;

  const int tid = threadIdx.x, lane = tid & 63, wave = tid >> 6;
  const int l15 = lane & 15, quad = lane >> 4;
  const int qbase = qx * 256 + wave * 32;
  const float scale2 = 0.12752358514837517f;  // (1/sqrt(128)) * log2(e)
  const float NEGINF = -__builtin_inff();
  __shared__ u16 Ksm[2][2][32 * 128];  // [buf][sub][row*128+c], cc' = cc ^ (row&7)
  __shared__ u16 Vsm[2][2][128 * 32];  // [buf][sub][d*32+c], chunk' = chunk ^ ((d>>1)&3)

  short8 qf[2][4];
#pragma unroll
  for (int h2 = 0; h2 < 2; ++h2) {
    const u16* qb = Q + ((size_t)(b * 4096 + qbase + h2 * 16 + l15)) * 2048 + h * 128 + quad * 8;
#pragma unroll
    for (int kc = 0; kc < 4; ++kc) qf[h2][kc] = *(const short8*)(qb + kc * 32);
  }

  // staging maps: 512 threads cover each 512-chunk sub-tile with 1 GLDS16
  const int krow = tid >> 4;                           // 0..31
  const int kcc = ((tid & 15) ^ (krow & 7)) * 8;       // swizzled K source col
  const int vd = tid >> 2;                             // 0..127
  const int vcs = ((tid & 3) ^ ((vd >> 1) & 3)) * 8;   // swizzled V source chunk
  const int kxor = l15 & 7;
  const int vxor = (l15 >> 1) & 3;

  f32x4 accv[2][8];
  u16x4 oimg[2][8];
  float run_m[2], run_l[2];

  auto phase = [&](const u16* Kb, const u16* Vb, int Lv, int LK) {
    run_m[0] = run_m[1] = NEGINF;
    run_l[0] = run_l[1] = 0.f;
#pragma unroll
    for (int h2 = 0; h2 < 2; ++h2)
#pragma unroll
      for (int dt = 0; dt < 8; ++dt)
#pragma unroll
        for (int r = 0; r < 4; ++r) accv[h2][dt][r] = 0.f;
    const u16* kg = Kb + (size_t)krow * 2048 + kcc;
    const u16* vg = Vb + (size_t)vd * LK + vcs;
    const int ntiles = (Lv + 63) >> 6;
    auto stage = [&](int buf, int t) {
      const int kvA = t * 64;
      const int sA = (kvA < LK - 32) ? kvA : (LK - 32);
      const int sB = (kvA + 32 < LK - 32) ? (kvA + 32) : (LK - 32);
      GLDS16(kg + (size_t)sA * 2048, &Ksm[buf][0][tid * 8]);
      GLDS16(kg + (size_t)sB * 2048, &Ksm[buf][1][tid * 8]);
      GLDS16(vg + sA, &Vsm[buf][0][tid * 8]);
      GLDS16(vg + sB, &Vsm[buf][1][tid * 8]);
    };
    stage(0, 0);
    __syncthreads();
    for (int t = 0; t < ntiles; ++t) {
      const int cb = t & 1;
      if (t + 1 < ntiles) stage(cb ^ 1, t + 1);

      // ---- QK^T: 4 key-16-blocks (sub A rows l15/16+l15, sub B same) ----
      f32x4 s[2][4];
#pragma unroll
      for (int h2 = 0; h2 < 2; ++h2)
#pragma unroll
        for (int kb = 0; kb < 4; ++kb)
#pragma unroll
          for (int r = 0; r < 4; ++r) s[h2][kb][r] = 0.f;
      {
        short8 kA[2][4];
#pragma unroll
        for (int kc = 0; kc < 4; ++kc) {
          const int c0 = ((kc * 4 + quad) ^ kxor) * 8;
          kA[0][kc] = *(const short8*)(&Ksm[cb][0][l15 * 128 + c0]);
          kA[1][kc] = *(const short8*)(&Ksm[cb][0][(16 + l15) * 128 + c0]);
        }
        __builtin_amdgcn_s_setprio(1);
#pragma unroll
        for (int h2 = 0; h2 < 2; ++h2)
#pragma unroll
          for (int kc = 0; kc < 4; ++kc) {
            s[h2][0] = MFMA32(kA[0][kc], qf[h2][kc], s[h2][0]);
            s[h2][1] = MFMA32(kA[1][kc], qf[h2][kc], s[h2][1]);
          }
        __builtin_amdgcn_s_setprio(0);
      }
      {
        short8 kB[2][4];
#pragma unroll
        for (int kc = 0; kc < 4; ++kc) {
          const int c0 = ((kc * 4 + quad) ^ kxor) * 8;
          kB[0][kc] = *(const short8*)(&Ksm[cb][1][l15 * 128 + c0]);
          kB[1][kc] = *(const short8*)(&Ksm[cb][1][(16 + l15) * 128 + c0]);
        }
        __builtin_amdgcn_s_setprio(1);
#pragma unroll
        for (int h2 = 0; h2 < 2; ++h2)
#pragma unroll
          for (int kc = 0; kc < 4; ++kc) {
            s[h2][2] = MFMA32(kB[0][kc], qf[h2][kc], s[h2][2]);
            s[h2][3] = MFMA32(kB[1][kc], qf[h2][kc], s[h2][3]);
          }
        __builtin_amdgcn_s_setprio(0);
      }

      // ---- tail mask in RAW score units ----
      const int kvA = t * 64;
      if (kvA + 64 > Lv) {
#pragma unroll
        for (int h2 = 0; h2 < 2; ++h2)
#pragma unroll
          for (int kb = 0; kb < 4; ++kb)
#pragma unroll
            for (int r = 0; r < 4; ++r) {
              const int ki = kvA + kb * 16 + quad * 4 + r;
              if (ki >= Lv) s[h2][kb][r] = NEGINF;
            }
      }

      // ---- one softmax pass over 64 keys ----
      float al[2];
      short8 pfA[2], pfB[2];
#pragma unroll
      for (int h2 = 0; h2 < 2; ++h2) {
        float m0 = fmaxf(fmaxf(s[h2][0][0], s[h2][0][1]), fmaxf(s[h2][0][2], s[h2][0][3]));
        float m1 = fmaxf(fmaxf(s[h2][1][0], s[h2][1][1]), fmaxf(s[h2][1][2], s[h2][1][3]));
        float m2 = fmaxf(fmaxf(s[h2][2][0], s[h2][2][1]), fmaxf(s[h2][2][2], s[h2][2][3]));
        float m3 = fmaxf(fmaxf(s[h2][3][0], s[h2][3][1]), fmaxf(s[h2][3][2], s[h2][3][3]));
        float mx = fmaxf(fmaxf(m0, m1), fmaxf(m2, m3));
        mx = fmaxf(mx, __shfl_xor(mx, 16, 64));
        mx = fmaxf(mx, __shfl_xor(mx, 32, 64));
        const float nm = fmaxf(run_m[h2], mx);
        al[h2] = EXP2F((run_m[h2] - nm) * scale2);
        run_m[h2] = nm;
        const float nmc = -nm * scale2;
        float p[4][4], psum = 0.f;
#pragma unroll
        for (int kb = 0; kb < 4; ++kb)
#pragma unroll
          for (int r = 0; r < 4; ++r) {
            p[kb][r] = EXP2F(__builtin_fmaf(s[h2][kb][r], scale2, nmc));
            psum += p[kb][r];
          }
        run_l[h2] = __builtin_fmaf(run_l[h2], al[h2], psum);
        union { short8 s8; unsigned u[4]; } pa, pb;
        pa.u[0] = cvtpk_bf16(p[0][0], p[0][1]);
        pa.u[1] = cvtpk_bf16(p[0][2], p[0][3]);
        pa.u[2] = cvtpk_bf16(p[1][0], p[1][1]);
        pa.u[3] = cvtpk_bf16(p[1][2], p[1][3]);
        pb.u[0] = cvtpk_bf16(p[2][0], p[2][1]);
        pb.u[1] = cvtpk_bf16(p[2][2], p[2][3]);
        pb.u[2] = cvtpk_bf16(p[3][0], p[3][1]);
        pb.u[3] = cvtpk_bf16(p[3][2], p[3][3]);
        pfA[h2] = pa.s8;
        pfB[h2] = pb.s8;
      }
      // skip accumulator rescale when no lane's max moved (al==1 exactly)
      if (t != 0 && __ballot((al[0] < 1.0f) || (al[1] < 1.0f))) {
#pragma unroll
        for (int h2 = 0; h2 < 2; ++h2)
#pragma unroll
          for (int dt = 0; dt < 8; ++dt)
#pragma unroll
            for (int r = 0; r < 4; ++r) accv[h2][dt][r] *= al[h2];
      }

      // ---- PV: both 32-key halves ----
      __builtin_amdgcn_s_setprio(1);
#pragma unroll
      for (int dt = 0; dt < 8; ++dt) {
        const int vo = (dt * 16 + l15) * 32 + ((quad ^ vxor) * 8);
        short8 vfA = *(const short8*)(&Vsm[cb][0][vo]);
        short8 vfB = *(const short8*)(&Vsm[cb][1][vo]);
        accv[0][dt] = MFMA32(vfA, pfA[0], accv[0][dt]);
        accv[1][dt] = MFMA32(vfA, pfA[1], accv[1][dt]);
        accv[0][dt] = MFMA32(vfB, pfB[0], accv[0][dt]);
        accv[1][dt] = MFMA32(vfB, pfB[1], accv[1][dt]);
      }
      __builtin_amdgcn_s_setprio(0);
      __syncthreads();
    }
  };

  // ---- img phase ----
  const u16* Kb_i = Ki + (size_t)(b * 288) * 2048 + h * 128;
  const u16* Vb_i = Vi + ((size_t)(b * 16 + h) * 128) * 288;
  phase(Kb_i, Vb_i, 257, 288);
#pragma unroll
  for (int h2 = 0; h2 < 2; ++h2) {
    float a = run_l[h2] + __shfl_xor(run_l[h2], 16, 64);
    float lt = a + __shfl_xor(a, 32, 64);
    float inv = 1.0f / lt;
#pragma unroll
    for (int dt = 0; dt < 8; ++dt) {
      u16x4 w2 = { f2bf(accv[h2][dt][0] * inv), f2bf(accv[h2][dt][1] * inv),
                   f2bf(accv[h2][dt][2] * inv), f2bf(accv[h2][dt][3] * inv) };
      oimg[h2][dt] = w2;
    }
  }
  // ---- txt phase ----
  const u16* Kb_t = Kt + (size_t)(b * 512) * 2048 + h * 128;
  const u16* Vb_t = Vt + ((size_t)(b * 16 + h) * 128) * 512;
  phase(Kb_t, Vb_t, lens[b], 512);
#pragma unroll
  for (int h2 = 0; h2 < 2; ++h2) {
    float a = run_l[h2] + __shfl_xor(run_l[h2], 16, 64);
    float lt = a + __shfl_xor(a, 32, 64);
    float inv = 1.0f / lt;
    u16* ob = out + ((size_t)(b * 4096 + qbase + h2 * 16 + l15)) * 2048 + h * 128 + quad * 4;
#pragma unroll
    for (int dt = 0; dt < 8; ++dt) {
      u16x4 w2 = { f2bf(bf2f(oimg[h2][dt][0]) + accv[h2][dt][0] * inv),
                   f2bf(bf2f(oimg[h2][dt][1]) + accv[h2][dt][1] * inv),
                   f2bf(bf2f(oimg[h2][dt][2]) + accv[h2][dt][2] * inv),
                   f2bf(bf2f(oimg[h2][dt][3]) + accv[h2][dt][3] * inv) };
      *(u16x4*)(ob + dt * 16) = w2;
    }
  }
}

extern "C" void kernel_launch(void* const* d_in, const int* in_sizes, int n_in,
                              void* d_out, int out_size, void* d_ws, size_t ws_size,
                              hipStream_t stream) {
  const float* x   = (const float*)d_in[0];
  const float* ctx = (const float*)d_in[1];
  const int* lens  = (const int*)d_in[2];
  const float* Wq  = (const float*)d_in[3];
  const float* bq  = (const float*)d_in[4];
  const float* gq  = (const float*)d_in[5];
  const float* Wk  = (const float*)d_in[6];
  const float* bk  = (const float*)d_in[7];
  const float* gk  = (const float*)d_in[8];
  const float* Wv  = (const float*)d_in[9];
  const float* bv  = (const float*)d_in[10];
  const float* Wki = (const float*)d_in[11];
  const float* bki = (const float*)d_in[12];
  const float* gki = (const float*)d_in[13];
  const float* Wvi = (const float*)d_in[14];
  const float* bvi = (const float*)d_in[15];
  const float* Wo  = (const float*)d_in[16];
  const float* bo  = (const float*)d_in[17];
  float* out = (float*)d_out;

  char* p = (char*)d_ws;
  u16* x_bf   = (u16*)p; p += (size_t)8192 * 2048 * 2;     // reused as attn_out
  u16* ctx_bf = (u16*)p; p += (size_t)2 * 769 * 2048 * 2;
  u16* Wt     = (u16*)p; p += (size_t)6 * 2048 * 2048 * 2;
  u16* Qb     = (u16*)p; p += (size_t)8192 * 2048 * 2;
  u16* Ktxt   = (u16*)p; p += (size_t)2 * 512 * 2048 * 2;
  u16* Vtt    = (u16*)p; p += (size_t)2 * 16 * 128 * 512 * 2;
  u16* Kimg   = (u16*)p; p += (size_t)2 * 288 * 2048 * 2;
  u16* Vti    = (u16*)p; p += (size_t)2 * 16 * 128 * 288 * 2;
  u16* attn_o = x_bf;

  cast_bf16_k<<<16384, 256, 0, stream>>>(x, x_bf, 8192 * 2048 / 4);
  cast_bf16_k<<<3076, 256, 0, stream>>>(ctx, ctx_bf, 2 * 769 * 2048 / 4);
  transw_k<<<dim3(32, 32, 6), 256, 0, stream>>>(Wq, Wk, Wv, Wki, Wvi, Wo, Wt);

  // Q projection: 8192x2048x2048 -> bf16
  gemm256_k<<<dim3(32, 8), 512, 0, stream>>>(x_bf, Wt + 0ull * 4194304, bq, Qb, 0);

  GemmJobs jc = {};
  for (int b = 0; b < 2; ++b) {
    const u16* txtA = ctx_bf + (size_t)(b * 769 + 257) * 2048;
    const u16* imgA = ctx_bf + (size_t)(b * 769) * 2048;
    jc.j[0 + b] = { txtA, Wt + 1ull * 4194304, bk,  Ktxt + (size_t)b * 512 * 2048, 512, 0, 2048 };
    jc.j[2 + b] = { txtA, Wt + 2ull * 4194304, bv,  Vtt  + (size_t)b * 2048 * 512, 512, 1, 512 };
    jc.j[4 + b] = { imgA, Wt + 3ull * 4194304, bki, Kimg + (size_t)b * 288 * 2048, 257, 0, 2048 };
    jc.j[6 + b] = { imgA, Wt + 4ull * 4194304, bvi, Vti  + (size_t)b * 2048 * 288, 257, 1, 288 };
  }
  gemm_k<<<dim3(4, 16, 8), 256, 0, stream>>>(jc);

  rmsnorm_k<<<8192, 256, 0, stream>>>(Qb, gq);
  rmsnorm_k<<<1024, 256, 0, stream>>>(Ktxt, gk);
  rmsnorm_k<<<576, 256, 0, stream>>>(Kimg, gki);

  attn_k<<<dim3(16, 16, 2), 512, 0, stream>>>(Qb, Ktxt, Vtt, Kimg, Vti, lens, attn_o);

  // output projection: 8192x2048x2048 -> fp32
  gemm256_k<<<dim3(32, 8), 512, 0, stream>>>(attn_o, Wt + 5ull * 4194304, bo, out, 1);
}

// Round 5
// 514.244 us; speedup vs baseline: 1.1572x; 1.0014x over previous
//
#include <hip/hip_runtime.h>

typedef unsigned short u16;
typedef short short8 __attribute__((ext_vector_type(8)));
typedef float f32x4 __attribute__((ext_vector_type(4)));
typedef unsigned short u16x4 __attribute__((ext_vector_type(4)));

__device__ __forceinline__ u16 f2bf(float f) {
  unsigned u = __builtin_bit_cast(unsigned, f);
  u += 0x7fffu + ((u >> 16) & 1u);
  return (u16)(u >> 16);
}
__device__ __forceinline__ float bf2f(u16 s) {
  unsigned u = ((unsigned)s) << 16;
  return __builtin_bit_cast(float, u);
}
// packed f32x2 -> bf16x2 (lo = a, hi = b), RNE — gfx950 has no builtin (T12)
__device__ __forceinline__ unsigned cvtpk_bf16(float a, float b) {
  unsigned r;
  asm("v_cvt_pk_bf16_f32 %0, %1, %2" : "=v"(r) : "v"(a), "v"(b));
  return r;
}

#if __has_builtin(__builtin_amdgcn_exp2f)
#define EXP2F(x) __builtin_amdgcn_exp2f(x)
#else
#define EXP2F(x) exp2f(x)
#endif

#define MFMA32(a, b, c) __builtin_amdgcn_mfma_f32_16x16x32_bf16(a, b, c, 0, 0, 0)

#define GLDS16(gp, lp)                                                         \
  __builtin_amdgcn_global_load_lds(                                            \
      (__attribute__((address_space(1))) void*)(gp),                           \
      (__attribute__((address_space(3))) void*)(lp), 16, 0, 0)

// ---------------- cast fp32 -> bf16 ----------------
__global__ __launch_bounds__(256) void cast_bf16_k(const float* __restrict__ in,
                                                   u16* __restrict__ out, int n4) {
  int i = blockIdx.x * 256 + threadIdx.x;
  if (i >= n4) return;
  float4 v = ((const float4*)in)[i];
  u16x4 o = { f2bf(v.x), f2bf(v.y), f2bf(v.z), f2bf(v.w) };
  ((u16x4*)out)[i] = o;
}

// ---------------- weight transpose+cast: Wt[n][k] = W[k][n] ----------------
__global__ __launch_bounds__(256) void transw_k(const float* W0, const float* W1,
                                                const float* W2, const float* W3,
                                                const float* W4, const float* W5,
                                                u16* __restrict__ Wt) {
  int z = blockIdx.z;
  const float* W = z == 0 ? W0 : z == 1 ? W1 : z == 2 ? W2 : z == 3 ? W3 : z == 4 ? W4 : W5;
  u16* T = Wt + (size_t)z * 2048 * 2048;
  __shared__ float tile[64][65];
  int k0 = blockIdx.x * 64, n0 = blockIdx.y * 64;
  int c4 = (threadIdx.x & 15) * 4;
  int r = threadIdx.x >> 4;  // 0..15
#pragma unroll
  for (int i = 0; i < 4; ++i) {
    int row = r + i * 16;
    float4 v = *(const float4*)(W + (size_t)(k0 + row) * 2048 + n0 + c4);
    tile[row][c4 + 0] = v.x; tile[row][c4 + 1] = v.y;
    tile[row][c4 + 2] = v.z; tile[row][c4 + 3] = v.w;
  }
  __syncthreads();
#pragma unroll
  for (int i = 0; i < 4; ++i) {
    int nrow = r + i * 16;
    u16x4 o = { f2bf(tile[c4 + 0][nrow]), f2bf(tile[c4 + 1][nrow]),
                f2bf(tile[c4 + 2][nrow]), f2bf(tile[c4 + 3][nrow]) };
    *(u16x4*)(T + (size_t)(n0 + nrow) * 2048 + k0 + c4) = o;
  }
}

// ---------------- small-M GEMM (K/V projections): out = A * Wt^T + bias ----------------
// R5: double-buffered stage-ahead (single barrier per K-step) — same
// structure that took gemm256 to ~916 TF in R2.
struct GemmJob {
  const u16* A; const u16* Bt; const float* bias; void* out;
  int M; int mode; int ldo;
};
struct GemmJobs { GemmJob j[8]; };

__global__ __launch_bounds__(256) void gemm_k(GemmJobs jobs) {
  GemmJob J = jobs.j[blockIdx.z];
  const int m0 = blockIdx.x * 128;
  if (m0 >= J.M) return;
  const int n0 = blockIdx.y * 128;
  __shared__ u16 Asm[2][128 * 32];
  __shared__ u16 Bsm[2][128 * 32];
  const int tid = threadIdx.x;
  const int lane = tid & 63;
  const int l15 = lane & 15, quad = lane >> 4;
  const int wave = tid >> 6;
  const int wr = (wave >> 1) * 64, wc = (wave & 1) * 64;
  f32x4 acc[4][4] = {};
  const int g0 = tid, g1 = tid + 256;
  const u16* ag0 = J.A + (size_t)(m0 + (g0 >> 2)) * 2048 + (g0 & 3) * 8;
  const u16* ag1 = J.A + (size_t)(m0 + (g1 >> 2)) * 2048 + (g1 & 3) * 8;
  const u16* bg0 = J.Bt + (size_t)(n0 + (g0 >> 2)) * 2048 + (g0 & 3) * 8;
  const u16* bg1 = J.Bt + (size_t)(n0 + (g1 >> 2)) * 2048 + (g1 & 3) * 8;

  auto stage = [&](int buf, int k0) {
    GLDS16(ag0 + k0, &Asm[buf][g0 * 8]);
    GLDS16(ag1 + k0, &Asm[buf][g1 * 8]);
    GLDS16(bg0 + k0, &Bsm[buf][g0 * 8]);
    GLDS16(bg1 + k0, &Bsm[buf][g1 * 8]);
  };
  stage(0, 0);
  for (int k0 = 0; k0 < 2048; k0 += 32) {
    const int cb = (k0 >> 5) & 1;
    __syncthreads();  // drains tile's loads, issued a full K-step ago
    if (k0 + 32 < 2048) stage(cb ^ 1, k0 + 32);
    short8 af[4], bf[4];
#pragma unroll
    for (int mi = 0; mi < 4; ++mi)
      af[mi] = *(const short8*)(&Asm[cb][(wr + mi * 16 + l15) * 32 + quad * 8]);
#pragma unroll
    for (int ni = 0; ni < 4; ++ni)
      bf[ni] = *(const short8*)(&Bsm[cb][(wc + ni * 16 + l15) * 32 + quad * 8]);
    __builtin_amdgcn_s_setprio(1);
#pragma unroll
    for (int mi = 0; mi < 4; ++mi)
#pragma unroll
      for (int ni = 0; ni < 4; ++ni)
        acc[mi][ni] = __builtin_amdgcn_mfma_f32_16x16x32_bf16(af[mi], bf[ni], acc[mi][ni], 0, 0, 0);
    __builtin_amdgcn_s_setprio(0);
  }
#pragma unroll
  for (int mi = 0; mi < 4; ++mi) {
#pragma unroll
    for (int ni = 0; ni < 4; ++ni) {
      int nn = n0 + wc + ni * 16 + l15;
      float bv = J.bias[nn];
#pragma unroll
      for (int r = 0; r < 4; ++r) {
        int mm = m0 + wr + mi * 16 + quad * 4 + r;
        if (mm >= J.M) continue;
        float v = acc[mi][ni][r] + bv;
        if (J.mode == 0) {
          ((u16*)J.out)[(size_t)mm * J.ldo + nn] = f2bf(v);
        } else if (J.mode == 1) {
          int ml = mm & 31;
          int mp = (mm & ~31) | (((ml >> 2) & 3) * 8 + (ml >> 4) * 4 + (ml & 3));
          ((u16*)J.out)[(size_t)nn * J.ldo + mp] = f2bf(v);
        } else {
          ((float*)J.out)[(size_t)mm * J.ldo + nn] = v;
        }
      }
    }
  }
}

// ---------------- big GEMM: 256x256 tile, BK=32, depth-2 counted-vmcnt ----------------
// R5 (T4): 3 LDS buffers (96 KiB), depth-2 prefetch. Per tile:
// s_waitcnt vmcnt(4) waits ONLY tile t's 4 loads (issued two tiles ago,
// ~2x640 cyc of MFMA cover > ~900 cyc HBM latency); tile t+1's 4 stay in
// flight across the barrier — the VMEM queue never drains (m218: counted
// vs drain-0 = +38%). Stage-after-barrier makes the rotation race-free:
// buf (t+2)%3 was last read at iter t-1, and every wave passing the
// barrier finished that compute. Grid is 256 blocks = 1/CU, so the 96 KiB
// LDS costs nothing (only 1 block was ever resident).
__global__ __launch_bounds__(512, 2) void gemm256_k(const u16* __restrict__ A,
                                                    const u16* __restrict__ Bt,
                                                    const float* __restrict__ bias,
                                                    void* __restrict__ out,
                                                    int mode) {
  const int m0 = blockIdx.x * 256, n0 = blockIdx.y * 256;
  __shared__ u16 lds[3][2][256 * 32];  // [buf][A,B][row*32 + col], 96 KiB
  const int tid = threadIdx.x, lane = tid & 63;
  const int l15 = lane & 15, quad = lane >> 4;
  const int wave = tid >> 6;
  const int wr = wave >> 2;   // 0..1 : M half (128 rows)
  const int wc = wave & 3;    // 0..3 : N quarter (64 cols)
  const int srow = tid >> 2;                       // 0..127
  const int sc = ((tid & 3) ^ ((srow >> 1) & 3)) * 8;  // pre-swizzled source col
  const u16* Ag = A + (size_t)(m0 + srow) * 2048 + sc;
  const u16* Bg = Bt + (size_t)(n0 + srow) * 2048 + sc;
  const int lxor = (l15 >> 1) & 3;                 // read-side swizzle
  f32x4 acc[8][4] = {};

  auto stage = [&](int buf, int kt) {
    const size_t ko = (size_t)kt * 32;
    u16* dA = &lds[buf][0][tid * 8];
    u16* dB = &lds[buf][1][tid * 8];
    GLDS16(Ag + ko, dA);
    GLDS16(Ag + (size_t)128 * 2048 + ko, dA + 4096);
    GLDS16(Bg + ko, dB);
    GLDS16(Bg + (size_t)128 * 2048 + ko, dB + 4096);
  };

  stage(0, 0);
  stage(1, 1);
  int cb = 0;
  for (int t = 0; t < 64; ++t) {
    if (t < 63) asm volatile("s_waitcnt vmcnt(4)" ::: "memory");
    else        asm volatile("s_waitcnt vmcnt(0)" ::: "memory");
    __builtin_amdgcn_s_barrier();
    if (t + 2 < 64) stage((cb == 0) ? 2 : cb - 1, t + 2);
    const u16* Ab = &lds[cb][0][(size_t)wr * 128 * 32];
    const u16* Bb = &lds[cb][1][0];
    short8 bfr[4];
#pragma unroll
    for (int ni = 0; ni < 4; ++ni) {
      const int rn = wc * 64 + ni * 16 + l15;
      bfr[ni] = *(const short8*)(Bb + rn * 32 + ((quad ^ lxor) * 8));
    }
#pragma unroll
    for (int mi = 0; mi < 8; ++mi) {
      const int rm = mi * 16 + l15;
      short8 a = *(const short8*)(Ab + rm * 32 + ((quad ^ lxor) * 8));
      __builtin_amdgcn_s_setprio(1);
#pragma unroll
      for (int ni = 0; ni < 4; ++ni)
        acc[mi][ni] = MFMA32(a, bfr[ni], acc[mi][ni]);
      __builtin_amdgcn_s_setprio(0);
    }
    cb = (cb == 2) ? 0 : cb + 1;
  }
#pragma unroll
  for (int mi = 0; mi < 8; ++mi) {
#pragma unroll
    for (int ni = 0; ni < 4; ++ni) {
      const int nn = n0 + wc * 64 + ni * 16 + l15;
      const float bv = bias[nn];
      const int mm = m0 + wr * 128 + mi * 16 + quad * 4;
      if (mode == 0) {
        u16* op = (u16*)out + (size_t)mm * 2048 + nn;
#pragma unroll
        for (int r = 0; r < 4; ++r) op[(size_t)r * 2048] = f2bf(acc[mi][ni][r] + bv);
      } else {
        float* op = (float*)out + (size_t)mm * 2048 + nn;
#pragma unroll
        for (int r = 0; r < 4; ++r) op[(size_t)r * 2048] = acc[mi][ni][r] + bv;
      }
    }
  }
}

// ---------------- RMSNorm in place (rows of 2048 bf16) ----------------
__global__ __launch_bounds__(256) void rmsnorm_k(u16* __restrict__ buf,
                                                 const float* __restrict__ g) {
  const int row = blockIdx.x, tid = threadIdx.x;
  u16* p = buf + (size_t)row * 2048 + tid * 8;
  short8 v = *(short8*)p;
  float x[8]; float s = 0.f;
#pragma unroll
  for (int i = 0; i < 8; ++i) { x[i] = bf2f((u16)v[i]); s += x[i] * x[i]; }
#pragma unroll
  for (int o = 1; o < 64; o <<= 1) s += __shfl_xor(s, o, 64);
  __shared__ float ws4[4];
  if ((tid & 63) == 0) ws4[tid >> 6] = s;
  __syncthreads();
  float tot = ws4[0] + ws4[1] + ws4[2] + ws4[3];
  float scale = rsqrtf(tot * (1.0f / 2048.0f) + 1e-6f);
  const float* gp = g + tid * 8;
  short8 o8;
#pragma unroll
  for (int i = 0; i < 8; ++i) o8[i] = (short)f2bf(x[i] * scale * gp[i]);
  *(short8*)p = o8;
}

// ---------------- flash attention ----------------
// R4 structure (KVBLK=64, 8-wave/512-thread, 256 q-rows/block) + R5: T13
// defer-max — keep the old running max while the tile max grows by <= 62
// raw-score units (= 2^8 in exp2 domain, bf16/f32-accum safe), so the
// O(64)-wide rescale and max-update are skipped on almost every tile.
__global__ __launch_bounds__(512) void attn_k(const u16* __restrict__ Q,
                                              const u16* __restrict__ Kt,
                                              const u16* __restrict__ Vt,
                                              const u16* __restrict__ Ki,
                                              const u16* __restrict__ Vi,
                                              const int* __restrict__ lens,
                                              u16* __restrict__ out) {
  // bijective XCD swizzle of the 16x16x2 grid (512 = 8 XCDs x 64)
  const int lid = blockIdx.x + 16 * (blockIdx.y + 16 * blockIdx.z);
  const int w = (lid & 7) * 64 + (lid >> 3);
  const int qx = w & 15, hb = w >> 4;
  const int h = hb & 15, b = hb >> 4;

  const int tid = threadIdx.x, lane = tid & 63, wave = tid >> 6;
  const int l15 = lane & 15, quad = lane >> 4;
  const int qbase = qx * 256 + wave * 32;
  const float scale2 = 0.12752358514837517f;  // (1/sqrt(128)) * log2(e)
  const float NEGINF = -__builtin_inff();
  __shared__ u16 Ksm[2][2][32 * 128];  // [buf][sub][row*128+c], cc' = cc ^ (row&7)
  __shared__ u16 Vsm[2][2][128 * 32];  // [buf][sub][d*32+c], chunk' = chunk ^ ((d>>1)&3)

  short8 qf[2][4];
#pragma unroll
  for (int h2 = 0; h2 < 2; ++h2) {
    const u16* qb = Q + ((size_t)(b * 4096 + qbase + h2 * 16 + l15)) * 2048 + h * 128 + quad * 8;
#pragma unroll
    for (int kc = 0; kc < 4; ++kc) qf[h2][kc] = *(const short8*)(qb + kc * 32);
  }

  // staging maps: 512 threads cover each 512-chunk sub-tile with 1 GLDS16
  const int krow = tid >> 4;                           // 0..31
  const int kcc = ((tid & 15) ^ (krow & 7)) * 8;       // swizzled K source col
  const int vd = tid >> 2;                             // 0..127
  const int vcs = ((tid & 3) ^ ((vd >> 1) & 3)) * 8;   // swizzled V source chunk
  const int kxor = l15 & 7;
  const int vxor = (l15 >> 1) & 3;

  f32x4 accv[2][8];
  u16x4 oimg[2][8];
  float run_m[2], run_l[2];

  auto phase = [&](const u16* Kb, const u16* Vb, int Lv, int LK) {
    run_m[0] = run_m[1] = NEGINF;
    run_l[0] = run_l[1] = 0.f;
#pragma unroll
    for (int h2 = 0; h2 < 2; ++h2)
#pragma unroll
      for (int dt = 0; dt < 8; ++dt)
#pragma unroll
        for (int r = 0; r < 4; ++r) accv[h2][dt][r] = 0.f;
    const u16* kg = Kb + (size_t)krow * 2048 + kcc;
    const u16* vg = Vb + (size_t)vd * LK + vcs;
    const int ntiles = (Lv + 63) >> 6;
    auto stage = [&](int buf, int t) {
      const int kvA = t * 64;
      const int sA = (kvA < LK - 32) ? kvA : (LK - 32);
      const int sB = (kvA + 32 < LK - 32) ? (kvA + 32) : (LK - 32);
      GLDS16(kg + (size_t)sA * 2048, &Ksm[buf][0][tid * 8]);
      GLDS16(kg + (size_t)sB * 2048, &Ksm[buf][1][tid * 8]);
      GLDS16(vg + sA, &Vsm[buf][0][tid * 8]);
      GLDS16(vg + sB, &Vsm[buf][1][tid * 8]);
    };
    stage(0, 0);
    __syncthreads();
    for (int t = 0; t < ntiles; ++t) {
      const int cb = t & 1;
      if (t + 1 < ntiles) stage(cb ^ 1, t + 1);

      // ---- QK^T: 4 key-16-blocks ----
      f32x4 s[2][4];
#pragma unroll
      for (int h2 = 0; h2 < 2; ++h2)
#pragma unroll
        for (int kb = 0; kb < 4; ++kb)
#pragma unroll
          for (int r = 0; r < 4; ++r) s[h2][kb][r] = 0.f;
      {
        short8 kA[2][4];
#pragma unroll
        for (int kc = 0; kc < 4; ++kc) {
          const int c0 = ((kc * 4 + quad) ^ kxor) * 8;
          kA[0][kc] = *(const short8*)(&Ksm[cb][0][l15 * 128 + c0]);
          kA[1][kc] = *(const short8*)(&Ksm[cb][0][(16 + l15) * 128 + c0]);
        }
        __builtin_amdgcn_s_setprio(1);
#pragma unroll
        for (int h2 = 0; h2 < 2; ++h2)
#pragma unroll
          for (int kc = 0; kc < 4; ++kc) {
            s[h2][0] = MFMA32(kA[0][kc], qf[h2][kc], s[h2][0]);
            s[h2][1] = MFMA32(kA[1][kc], qf[h2][kc], s[h2][1]);
          }
        __builtin_amdgcn_s_setprio(0);
      }
      {
        short8 kB[2][4];
#pragma unroll
        for (int kc = 0; kc < 4; ++kc) {
          const int c0 = ((kc * 4 + quad) ^ kxor) * 8;
          kB[0][kc] = *(const short8*)(&Ksm[cb][1][l15 * 128 + c0]);
          kB[1][kc] = *(const short8*)(&Ksm[cb][1][(16 + l15) * 128 + c0]);
        }
        __builtin_amdgcn_s_setprio(1);
#pragma unroll
        for (int h2 = 0; h2 < 2; ++h2)
#pragma unroll
          for (int kc = 0; kc < 4; ++kc) {
            s[h2][2] = MFMA32(kB[0][kc], qf[h2][kc], s[h2][2]);
            s[h2][3] = MFMA32(kB[1][kc], qf[h2][kc], s[h2][3]);
          }
        __builtin_amdgcn_s_setprio(0);
      }

      // ---- tail mask in RAW score units ----
      const int kvA = t * 64;
      if (kvA + 64 > Lv) {
#pragma unroll
        for (int h2 = 0; h2 < 2; ++h2)
#pragma unroll
          for (int kb = 0; kb < 4; ++kb)
#pragma unroll
            for (int r = 0; r < 4; ++r) {
              const int ki = kvA + kb * 16 + quad * 4 + r;
              if (ki >= Lv) s[h2][kb][r] = NEGINF;
            }
      }

      // ---- one softmax pass over 64 keys (defer-max, THR = 62 raw = 2^8) ----
      float al[2];
      short8 pfA[2], pfB[2];
#pragma unroll
      for (int h2 = 0; h2 < 2; ++h2) {
        float m0 = fmaxf(fmaxf(s[h2][0][0], s[h2][0][1]), fmaxf(s[h2][0][2], s[h2][0][3]));
        float m1 = fmaxf(fmaxf(s[h2][1][0], s[h2][1][1]), fmaxf(s[h2][1][2], s[h2][1][3]));
        float m2 = fmaxf(fmaxf(s[h2][2][0], s[h2][2][1]), fmaxf(s[h2][2][2], s[h2][2][3]));
        float m3 = fmaxf(fmaxf(s[h2][3][0], s[h2][3][1]), fmaxf(s[h2][3][2], s[h2][3][3]));
        float mx = fmaxf(fmaxf(m0, m1), fmaxf(m2, m3));
        mx = fmaxf(mx, __shfl_xor(mx, 16, 64));
        mx = fmaxf(mx, __shfl_xor(mx, 32, 64));
        // defer-max: keep old running max unless the growth exceeds 62 raw
        // (P then bounded by 2^8; f32 accum has ample headroom)
        const float nm = (mx - run_m[h2] > 62.0f) ? mx : run_m[h2];
        al[h2] = EXP2F((run_m[h2] - nm) * scale2);
        run_m[h2] = nm;
        const float nmc = -nm * scale2;
        float p[4][4], psum = 0.f;
#pragma unroll
        for (int kb = 0; kb < 4; ++kb)
#pragma unroll
          for (int r = 0; r < 4; ++r) {
            p[kb][r] = EXP2F(__builtin_fmaf(s[h2][kb][r], scale2, nmc));
            psum += p[kb][r];
          }
        run_l[h2] = __builtin_fmaf(run_l[h2], al[h2], psum);
        union { short8 s8; unsigned u[4]; } pa, pb;
        pa.u[0] = cvtpk_bf16(p[0][0], p[0][1]);
        pa.u[1] = cvtpk_bf16(p[0][2], p[0][3]);
        pa.u[2] = cvtpk_bf16(p[1][0], p[1][1]);
        pa.u[3] = cvtpk_bf16(p[1][2], p[1][3]);
        pb.u[0] = cvtpk_bf16(p[2][0], p[2][1]);
        pb.u[1] = cvtpk_bf16(p[2][2], p[2][3]);
        pb.u[2] = cvtpk_bf16(p[3][0], p[3][1]);
        pb.u[3] = cvtpk_bf16(p[3][2], p[3][3]);
        pfA[h2] = pa.s8;
        pfB[h2] = pb.s8;
      }
      // rescale only when some lane's max actually moved (al < 1)
      if (t != 0 && __ballot((al[0] < 1.0f) || (al[1] < 1.0f))) {
#pragma unroll
        for (int h2 = 0; h2 < 2; ++h2)
#pragma unroll
          for (int dt = 0; dt < 8; ++dt)
#pragma unroll
            for (int r = 0; r < 4; ++r) accv[h2][dt][r] *= al[h2];
      }

      // ---- PV: both 32-key halves ----
      __builtin_amdgcn_s_setprio(1);
#pragma unroll
      for (int dt = 0; dt < 8; ++dt) {
        const int vo = (dt * 16 + l15) * 32 + ((quad ^ vxor) * 8);
        short8 vfA = *(const short8*)(&Vsm[cb][0][vo]);
        short8 vfB = *(const short8*)(&Vsm[cb][1][vo]);
        accv[0][dt] = MFMA32(vfA, pfA[0], accv[0][dt]);
        accv[1][dt] = MFMA32(vfA, pfA[1], accv[1][dt]);
        accv[0][dt] = MFMA32(vfB, pfB[0], accv[0][dt]);
        accv[1][dt] = MFMA32(vfB, pfB[1], accv[1][dt]);
      }
      __builtin_amdgcn_s_setprio(0);
      __syncthreads();
    }
  };

  // ---- img phase ----
  const u16* Kb_i = Ki + (size_t)(b * 288) * 2048 + h * 128;
  const u16* Vb_i = Vi + ((size_t)(b * 16 + h) * 128) * 288;
  phase(Kb_i, Vb_i, 257, 288);
#pragma unroll
  for (int h2 = 0; h2 < 2; ++h2) {
    float a = run_l[h2] + __shfl_xor(run_l[h2], 16, 64);
    float lt = a + __shfl_xor(a, 32, 64);
    float inv = 1.0f / lt;
#pragma unroll
    for (int dt = 0; dt < 8; ++dt) {
      u16x4 w2 = { f2bf(accv[h2][dt][0] * inv), f2bf(accv[h2][dt][1] * inv),
                   f2bf(accv[h2][dt][2] * inv), f2bf(accv[h2][dt][3] * inv) };
      oimg[h2][dt] = w2;
    }
  }
  // ---- txt phase ----
  const u16* Kb_t = Kt + (size_t)(b * 512) * 2048 + h * 128;
  const u16* Vb_t = Vt + ((size_t)(b * 16 + h) * 128) * 512;
  phase(Kb_t, Vb_t, lens[b], 512);
#pragma unroll
  for (int h2 = 0; h2 < 2; ++h2) {
    float a = run_l[h2] + __shfl_xor(run_l[h2], 16, 64);
    float lt = a + __shfl_xor(a, 32, 64);
    float inv = 1.0f / lt;
    u16* ob = out + ((size_t)(b * 4096 + qbase + h2 * 16 + l15)) * 2048 + h * 128 + quad * 4;
#pragma unroll
    for (int dt = 0; dt < 8; ++dt) {
      u16x4 w2 = { f2bf(bf2f(oimg[h2][dt][0]) + accv[h2][dt][0] * inv),
                   f2bf(bf2f(oimg[h2][dt][1]) + accv[h2][dt][1] * inv),
                   f2bf(bf2f(oimg[h2][dt][2]) + accv[h2][dt][2] * inv),
                   f2bf(bf2f(oimg[h2][dt][3]) + accv[h2][dt][3] * inv) };
      *(u16x4*)(ob + dt * 16) = w2;
    }
  }
}

extern "C" void kernel_launch(void* const* d_in, const int* in_sizes, int n_in,
                              void* d_out, int out_size, void* d_ws, size_t ws_size,
                              hipStream_t stream) {
  const float* x   = (const float*)d_in[0];
  const float* ctx = (const float*)d_in[1];
  const int* lens  = (const int*)d_in[2];
  const float* Wq  = (const float*)d_in[3];
  const float* bq  = (const float*)d_in[4];
  const float* gq  = (const float*)d_in[5];
  const float* Wk  = (const float*)d_in[6];
  const float* bk  = (const float*)d_in[7];
  const float* gk  = (const float*)d_in[8];
  const float* Wv  = (const float*)d_in[9];
  const float* bv  = (const float*)d_in[10];
  const float* Wki = (const float*)d_in[11];
  const float* bki = (const float*)d_in[12];
  const float* gki = (const float*)d_in[13];
  const float* Wvi = (const float*)d_in[14];
  const float* bvi = (const float*)d_in[15];
  const float* Wo  = (const float*)d_in[16];
  const float* bo  = (const float*)d_in[17];
  float* out = (float*)d_out;

  char* p = (char*)d_ws;
  u16* x_bf   = (u16*)p; p += (size_t)8192 * 2048 * 2;     // reused as attn_out
  u16* ctx_bf = (u16*)p; p += (size_t)2 * 769 * 2048 * 2;
  u16* Wt     = (u16*)p; p += (size_t)6 * 2048 * 2048 * 2;
  u16* Qb     = (u16*)p; p += (size_t)8192 * 2048 * 2;
  u16* Ktxt   = (u16*)p; p += (size_t)2 * 512 * 2048 * 2;
  u16* Vtt    = (u16*)p; p += (size_t)2 * 16 * 128 * 512 * 2;
  u16* Kimg   = (u16*)p; p += (size_t)2 * 288 * 2048 * 2;
  u16* Vti    = (u16*)p; p += (size_t)2 * 16 * 128 * 288 * 2;
  u16* attn_o = x_bf;

  cast_bf16_k<<<16384, 256, 0, stream>>>(x, x_bf, 8192 * 2048 / 4);
  cast_bf16_k<<<3076, 256, 0, stream>>>(ctx, ctx_bf, 2 * 769 * 2048 / 4);
  transw_k<<<dim3(32, 32, 6), 256, 0, stream>>>(Wq, Wk, Wv, Wki, Wvi, Wo, Wt);

  // Q projection: 8192x2048x2048 -> bf16
  gemm256_k<<<dim3(32, 8), 512, 0, stream>>>(x_bf, Wt + 0ull * 4194304, bq, Qb, 0);

  GemmJobs jc = {};
  for (int b = 0; b < 2; ++b) {
    const u16* txtA = ctx_bf + (size_t)(b * 769 + 257) * 2048;
    const u16* imgA = ctx_bf + (size_t)(b * 769) * 2048;
    jc.j[0 + b] = { txtA, Wt + 1ull * 4194304, bk,  Ktxt + (size_t)b * 512 * 2048, 512, 0, 2048 };
    jc.j[2 + b] = { txtA, Wt + 2ull * 4194304, bv,  Vtt  + (size_t)b * 2048 * 512, 512, 1, 512 };
    jc.j[4 + b] = { imgA, Wt + 3ull * 4194304, bki, Kimg + (size_t)b * 288 * 2048, 257, 0, 2048 };
    jc.j[6 + b] = { imgA, Wt + 4ull * 4194304, bvi, Vti  + (size_t)b * 2048 * 288, 257, 1, 288 };
  }
  gemm_k<<<dim3(4, 16, 8), 256, 0, stream>>>(jc);

  rmsnorm_k<<<8192, 256, 0, stream>>>(Qb, gq);
  rmsnorm_k<<<1024, 256, 0, stream>>>(Ktxt, gk);
  rmsnorm_k<<<576, 256, 0, stream>>>(Kimg, gki);

  attn_k<<<dim3(16, 16, 2), 512, 0, stream>>>(Qb, Ktxt, Vtt, Kimg, Vti, lens, attn_o);

  // output projection: 8192x2048x2048 -> fp32
  gemm256_k<<<dim3(32, 8), 512, 0, stream>>>(attn_o, Wt + 5ull * 4194304, bo, out, 1);
}

// Round 7
// 502.870 us; speedup vs baseline: 1.1834x; 1.0226x over previous
//
#include <hip/hip_runtime.h>

typedef unsigned short u16;
typedef short short8 __attribute__((ext_vector_type(8)));
typedef float f32x4 __attribute__((ext_vector_type(4)));
typedef unsigned short u16x4 __attribute__((ext_vector_type(4)));

__device__ __forceinline__ u16 f2bf(float f) {
  unsigned u = __builtin_bit_cast(unsigned, f);
  u += 0x7fffu + ((u >> 16) & 1u);
  return (u16)(u >> 16);
}
__device__ __forceinline__ float bf2f(u16 s) {
  unsigned u = ((unsigned)s) << 16;
  return __builtin_bit_cast(float, u);
}
// packed f32x2 -> bf16x2 (lo = a, hi = b), RNE — gfx950 has no builtin (T12)
__device__ __forceinline__ unsigned cvtpk_bf16(float a, float b) {
  unsigned r;
  asm("v_cvt_pk_bf16_f32 %0, %1, %2" : "=v"(r) : "v"(a), "v"(b));
  return r;
}

#if __has_builtin(__builtin_amdgcn_exp2f)
#define EXP2F(x) __builtin_amdgcn_exp2f(x)
#else
#define EXP2F(x) exp2f(x)
#endif

#define MFMA32(a, b, c) __builtin_amdgcn_mfma_f32_16x16x32_bf16(a, b, c, 0, 0, 0)

#define GLDS16(gp, lp)                                                         \
  __builtin_amdgcn_global_load_lds(                                            \
      (__attribute__((address_space(1))) void*)(gp),                           \
      (__attribute__((address_space(3))) void*)(lp), 16, 0, 0)

// ---------------- cast fp32 -> bf16 ----------------
__global__ __launch_bounds__(256) void cast_bf16_k(const float* __restrict__ in,
                                                   u16* __restrict__ out, int n4) {
  int i = blockIdx.x * 256 + threadIdx.x;
  if (i >= n4) return;
  float4 v = ((const float4*)in)[i];
  u16x4 o = { f2bf(v.x), f2bf(v.y), f2bf(v.z), f2bf(v.w) };
  ((u16x4*)out)[i] = o;
}

// ---------------- weight transpose+cast: Wt[n][k] = W[k][n] ----------------
__global__ __launch_bounds__(256) void transw_k(const float* W0, const float* W1,
                                                const float* W2, const float* W3,
                                                const float* W4, const float* W5,
                                                u16* __restrict__ Wt) {
  int z = blockIdx.z;
  const float* W = z == 0 ? W0 : z == 1 ? W1 : z == 2 ? W2 : z == 3 ? W3 : z == 4 ? W4 : W5;
  u16* T = Wt + (size_t)z * 2048 * 2048;
  __shared__ float tile[64][65];
  int k0 = blockIdx.x * 64, n0 = blockIdx.y * 64;
  int c4 = (threadIdx.x & 15) * 4;
  int r = threadIdx.x >> 4;  // 0..15
#pragma unroll
  for (int i = 0; i < 4; ++i) {
    int row = r + i * 16;
    float4 v = *(const float4*)(W + (size_t)(k0 + row) * 2048 + n0 + c4);
    tile[row][c4 + 0] = v.x; tile[row][c4 + 1] = v.y;
    tile[row][c4 + 2] = v.z; tile[row][c4 + 3] = v.w;
  }
  __syncthreads();
#pragma unroll
  for (int i = 0; i < 4; ++i) {
    int nrow = r + i * 16;
    u16x4 o = { f2bf(tile[c4 + 0][nrow]), f2bf(tile[c4 + 1][nrow]),
                f2bf(tile[c4 + 2][nrow]), f2bf(tile[c4 + 3][nrow]) };
    *(u16x4*)(T + (size_t)(n0 + nrow) * 2048 + k0 + c4) = o;
  }
}

// ---------------- small-M GEMM (K/V projections): out = A * Wt^T + bias ----------------
struct GemmJob {
  const u16* A; const u16* Bt; const float* bias; void* out;
  int M; int mode; int ldo;
};
struct GemmJobs { GemmJob j[8]; };

__global__ __launch_bounds__(256) void gemm_k(GemmJobs jobs) {
  GemmJob J = jobs.j[blockIdx.z];
  const int m0 = blockIdx.x * 128;
  if (m0 >= J.M) return;
  const int n0 = blockIdx.y * 128;
  __shared__ u16 Asm[2][128 * 32];
  __shared__ u16 Bsm[2][128 * 32];
  const int tid = threadIdx.x;
  const int lane = tid & 63;
  const int l15 = lane & 15, quad = lane >> 4;
  const int wave = tid >> 6;
  const int wr = (wave >> 1) * 64, wc = (wave & 1) * 64;
  f32x4 acc[4][4] = {};
  const int g0 = tid, g1 = tid + 256;
  const u16* ag0 = J.A + (size_t)(m0 + (g0 >> 2)) * 2048 + (g0 & 3) * 8;
  const u16* ag1 = J.A + (size_t)(m0 + (g1 >> 2)) * 2048 + (g1 & 3) * 8;
  const u16* bg0 = J.Bt + (size_t)(n0 + (g0 >> 2)) * 2048 + (g0 & 3) * 8;
  const u16* bg1 = J.Bt + (size_t)(n0 + (g1 >> 2)) * 2048 + (g1 & 3) * 8;

  auto stage = [&](int buf, int k0) {
    GLDS16(ag0 + k0, &Asm[buf][g0 * 8]);
    GLDS16(ag1 + k0, &Asm[buf][g1 * 8]);
    GLDS16(bg0 + k0, &Bsm[buf][g0 * 8]);
    GLDS16(bg1 + k0, &Bsm[buf][g1 * 8]);
  };
  stage(0, 0);
  for (int k0 = 0; k0 < 2048; k0 += 32) {
    const int cb = (k0 >> 5) & 1;
    __syncthreads();  // drains tile's loads, issued a full K-step ago
    if (k0 + 32 < 2048) stage(cb ^ 1, k0 + 32);
    short8 af[4], bf[4];
#pragma unroll
    for (int mi = 0; mi < 4; ++mi)
      af[mi] = *(const short8*)(&Asm[cb][(wr + mi * 16 + l15) * 32 + quad * 8]);
#pragma unroll
    for (int ni = 0; ni < 4; ++ni)
      bf[ni] = *(const short8*)(&Bsm[cb][(wc + ni * 16 + l15) * 32 + quad * 8]);
    __builtin_amdgcn_s_setprio(1);
#pragma unroll
    for (int mi = 0; mi < 4; ++mi)
#pragma unroll
      for (int ni = 0; ni < 4; ++ni)
        acc[mi][ni] = __builtin_amdgcn_mfma_f32_16x16x32_bf16(af[mi], bf[ni], acc[mi][ni], 0, 0, 0);
    __builtin_amdgcn_s_setprio(0);
  }
#pragma unroll
  for (int mi = 0; mi < 4; ++mi) {
#pragma unroll
    for (int ni = 0; ni < 4; ++ni) {
      int nn = n0 + wc + ni * 16 + l15;
      float bv = J.bias[nn];
#pragma unroll
      for (int r = 0; r < 4; ++r) {
        int mm = m0 + wr + mi * 16 + quad * 4 + r;
        if (mm >= J.M) continue;
        float v = acc[mi][ni][r] + bv;
        if (J.mode == 0) {
          ((u16*)J.out)[(size_t)mm * J.ldo + nn] = f2bf(v);
        } else if (J.mode == 1) {
          int ml = mm & 31;
          int mp = (mm & ~31) | (((ml >> 2) & 3) * 8 + (ml >> 4) * 4 + (ml & 3));
          ((u16*)J.out)[(size_t)nn * J.ldo + mp] = f2bf(v);
        } else {
          ((float*)J.out)[(size_t)mm * J.ldo + nn] = v;
        }
      }
    }
  }
}

// ---------------- big GEMM: 256x256 tile, BK=64, stage-ahead-1 ----------------
// R6: BK 32->64 amortizes the per-step fixed cost (stage issue + barrier +
// vmcnt(0) drain) over 2x the MFMA work (64 MFMA/wave/step) in the SAME
// proven 2-phase structure (R2: stage next tile before compute, one
// __syncthreads per step). LDS 128 KiB (2 buf x A,B x 256x64 bf16); grid is
// 256 blocks = 1/CU so there is no occupancy to lose. 8-chunk XOR swizzle
// (chunk' = chunk ^ (row&7)) applied identically on the pre-swizzled global
// source and the ds_read side (rule 21); bank group = chunk only, 64 lanes
// spread 8-per-group evenly -> schedulable conflict-free.
__global__ __launch_bounds__(512, 2) void gemm256_k(const u16* __restrict__ A,
                                                    const u16* __restrict__ Bt,
                                                    const float* __restrict__ bias,
                                                    void* __restrict__ out,
                                                    int mode) {
  const int m0 = blockIdx.x * 256, n0 = blockIdx.y * 256;
  __shared__ u16 lds[2][2][256 * 64];  // [buf][A,B][row*64 + col], 128 KiB
  const int tid = threadIdx.x, lane = tid & 63;
  const int l15 = lane & 15, quad = lane >> 4;
  const int wave = tid >> 6;
  const int wr = wave >> 2;   // 0..1 : M half (128 rows)
  const int wc = wave & 3;    // 0..3 : N quarter (64 cols)
  f32x4 acc[8][4] = {};

  // staging map: thread covers LDS 16B-chunks c = tid + 512*j, j=0..3;
  // row = c>>3, linear chunk (c&7) holds source chunk (c&7)^(row&7).
  auto stage = [&](int buf, int kt) {
    const int ko = kt * 64;
#pragma unroll
    for (int j = 0; j < 4; ++j) {
      const int c = tid + 512 * j;
      const int row = c >> 3;
      const int scc = (((c & 7) ^ (row & 7)) * 8);
      GLDS16(A + (size_t)(m0 + row) * 2048 + ko + scc, &lds[buf][0][(size_t)c * 8]);
      GLDS16(Bt + (size_t)(n0 + row) * 2048 + ko + scc, &lds[buf][1][(size_t)c * 8]);
    }
  };

  stage(0, 0);
  for (int t = 0; t < 32; ++t) {
    const int cb = t & 1;
    __syncthreads();  // vmcnt(0): drains tile t's loads (issued a full step ago)
    if (t + 1 < 32) stage(cb ^ 1, t + 1);
    const u16* Ab = &lds[cb][0][0];
    const u16* Bb = &lds[cb][1][0];
    short8 bfr[2][4];
#pragma unroll
    for (int kk = 0; kk < 2; ++kk)
#pragma unroll
      for (int ni = 0; ni < 4; ++ni) {
        const int rn = wc * 64 + ni * 16 + l15;
        bfr[kk][ni] = *(const short8*)(Bb + rn * 64 + (((kk * 4 + quad) ^ (rn & 7)) * 8));
      }
#pragma unroll
    for (int mi = 0; mi < 8; ++mi) {
      const int rm = wr * 128 + mi * 16 + l15;
      short8 a0 = *(const short8*)(Ab + rm * 64 + (((0 + quad) ^ (rm & 7)) * 8));
      short8 a1 = *(const short8*)(Ab + rm * 64 + (((4 + quad) ^ (rm & 7)) * 8));
      __builtin_amdgcn_s_setprio(1);
#pragma unroll
      for (int ni = 0; ni < 4; ++ni)
        acc[mi][ni] = MFMA32(a0, bfr[0][ni], acc[mi][ni]);
#pragma unroll
      for (int ni = 0; ni < 4; ++ni)
        acc[mi][ni] = MFMA32(a1, bfr[1][ni], acc[mi][ni]);
      __builtin_amdgcn_s_setprio(0);
    }
  }
#pragma unroll
  for (int mi = 0; mi < 8; ++mi) {
#pragma unroll
    for (int ni = 0; ni < 4; ++ni) {
      const int nn = n0 + wc * 64 + ni * 16 + l15;
      const float bv = bias[nn];
      const int mm = m0 + wr * 128 + mi * 16 + quad * 4;
      if (mode == 0) {
        u16* op = (u16*)out + (size_t)mm * 2048 + nn;
#pragma unroll
        for (int r = 0; r < 4; ++r) op[(size_t)r * 2048] = f2bf(acc[mi][ni][r] + bv);
      } else {
        float* op = (float*)out + (size_t)mm * 2048 + nn;
#pragma unroll
        for (int r = 0; r < 4; ++r) op[(size_t)r * 2048] = acc[mi][ni][r] + bv;
      }
    }
  }
}

// ---------------- RMSNorm in place (rows of 2048 bf16) ----------------
__global__ __launch_bounds__(256) void rmsnorm_k(u16* __restrict__ buf,
                                                 const float* __restrict__ g) {
  const int row = blockIdx.x, tid = threadIdx.x;
  u16* p = buf + (size_t)row * 2048 + tid * 8;
  short8 v = *(short8*)p;
  float x[8]; float s = 0.f;
#pragma unroll
  for (int i = 0; i < 8; ++i) { x[i] = bf2f((u16)v[i]); s += x[i] * x[i]; }
#pragma unroll
  for (int o = 1; o < 64; o <<= 1) s += __shfl_xor(s, o, 64);
  __shared__ float ws4[4];
  if ((tid & 63) == 0) ws4[tid >> 6] = s;
  __syncthreads();
  float tot = ws4[0] + ws4[1] + ws4[2] + ws4[3];
  float scale = rsqrtf(tot * (1.0f / 2048.0f) + 1e-6f);
  const float* gp = g + tid * 8;
  short8 o8;
#pragma unroll
  for (int i = 0; i < 8; ++i) o8[i] = (short)f2bf(x[i] * scale * gp[i]);
  *(short8*)p = o8;
}

// ---------------- flash attention ----------------
// R6: XCD mapping rebalanced. R3-R5 mapped batch b = w>>8, which sent ALL
// b=0 blocks to XCDs 0-3 and b=1 to XCDs 4-7 — with skewed context_lens
// half the chip idled (Occupancy 19%). New mapping gives each XCD 2 heads
// x both batches x all 16 q-tiles: balanced work AND per-XCD K/V slice
// ~1.6 MB (4 (b,h) pairs) still L2-resident.
__global__ __launch_bounds__(512) void attn_k(const u16* __restrict__ Q,
                                              const u16* __restrict__ Kt,
                                              const u16* __restrict__ Vt,
                                              const u16* __restrict__ Ki,
                                              const u16* __restrict__ Vi,
                                              const int* __restrict__ lens,
                                              u16* __restrict__ out) {
  const int lid = blockIdx.x + 16 * (blockIdx.y + 16 * blockIdx.z);  // [0,512)
  const int xcd = lid & 7, i = lid >> 3;   // i in [0,64)
  const int h = xcd * 2 + (i & 1);         // 2 heads per XCD
  const int b = (i >> 1) & 1;              // both batches per XCD
  const int qx = i >> 2;                   // [0,16)

  const int tid = threadIdx.x, lane = tid & 63, wave = tid >> 6;
  const int l15 = lane & 15, quad = lane >> 4;
  const int qbase = qx * 256 + wave * 32;
  const float scale2 = 0.12752358514837517f;  // (1/sqrt(128)) * log2(e)
  const float NEGINF = -__builtin_inff();
  __shared__ u16 Ksm[2][2][32 * 128];  // [buf][sub][row*128+c], cc' = cc ^ (row&7)
  __shared__ u16 Vsm[2][2][128 * 32];  // [buf][sub][d*32+c], chunk' = chunk ^ ((d>>1)&3)

  short8 qf[2][4];
#pragma unroll
  for (int h2 = 0; h2 < 2; ++h2) {
    const u16* qb = Q + ((size_t)(b * 4096 + qbase + h2 * 16 + l15)) * 2048 + h * 128 + quad * 8;
#pragma unroll
    for (int kc = 0; kc < 4; ++kc) qf[h2][kc] = *(const short8*)(qb + kc * 32);
  }

  const int krow = tid >> 4;                           // 0..31
  const int kcc = ((tid & 15) ^ (krow & 7)) * 8;       // swizzled K source col
  const int vd = tid >> 2;                             // 0..127
  const int vcs = ((tid & 3) ^ ((vd >> 1) & 3)) * 8;   // swizzled V source chunk
  const int kxor = l15 & 7;
  const int vxor = (l15 >> 1) & 3;

  f32x4 accv[2][8];
  u16x4 oimg[2][8];
  float run_m[2], run_l[2];

  auto phase = [&](const u16* Kb, const u16* Vb, int Lv, int LK) {
    run_m[0] = run_m[1] = NEGINF;
    run_l[0] = run_l[1] = 0.f;
#pragma unroll
    for (int h2 = 0; h2 < 2; ++h2)
#pragma unroll
      for (int dt = 0; dt < 8; ++dt)
#pragma unroll
        for (int r = 0; r < 4; ++r) accv[h2][dt][r] = 0.f;
    const u16* kg = Kb + (size_t)krow * 2048 + kcc;
    const u16* vg = Vb + (size_t)vd * LK + vcs;
    const int ntiles = (Lv + 63) >> 6;
    auto stage = [&](int buf, int t) {
      const int kvA = t * 64;
      const int sA = (kvA < LK - 32) ? kvA : (LK - 32);
      const int sB = (kvA + 32 < LK - 32) ? (kvA + 32) : (LK - 32);
      GLDS16(kg + (size_t)sA * 2048, &Ksm[buf][0][tid * 8]);
      GLDS16(kg + (size_t)sB * 2048, &Ksm[buf][1][tid * 8]);
      GLDS16(vg + sA, &Vsm[buf][0][tid * 8]);
      GLDS16(vg + sB, &Vsm[buf][1][tid * 8]);
    };
    stage(0, 0);
    __syncthreads();
    for (int t = 0; t < ntiles; ++t) {
      const int cb = t & 1;
      if (t + 1 < ntiles) stage(cb ^ 1, t + 1);

      // ---- QK^T: 4 key-16-blocks ----
      f32x4 s[2][4];
#pragma unroll
      for (int h2 = 0; h2 < 2; ++h2)
#pragma unroll
        for (int kb = 0; kb < 4; ++kb)
#pragma unroll
          for (int r = 0; r < 4; ++r) s[h2][kb][r] = 0.f;
      {
        short8 kA[2][4];
#pragma unroll
        for (int kc = 0; kc < 4; ++kc) {
          const int c0 = ((kc * 4 + quad) ^ kxor) * 8;
          kA[0][kc] = *(const short8*)(&Ksm[cb][0][l15 * 128 + c0]);
          kA[1][kc] = *(const short8*)(&Ksm[cb][0][(16 + l15) * 128 + c0]);
        }
        __builtin_amdgcn_s_setprio(1);
#pragma unroll
        for (int h2 = 0; h2 < 2; ++h2)
#pragma unroll
          for (int kc = 0; kc < 4; ++kc) {
            s[h2][0] = MFMA32(kA[0][kc], qf[h2][kc], s[h2][0]);
            s[h2][1] = MFMA32(kA[1][kc], qf[h2][kc], s[h2][1]);
          }
        __builtin_amdgcn_s_setprio(0);
      }
      {
        short8 kB[2][4];
#pragma unroll
        for (int kc = 0; kc < 4; ++kc) {
          const int c0 = ((kc * 4 + quad) ^ kxor) * 8;
          kB[0][kc] = *(const short8*)(&Ksm[cb][1][l15 * 128 + c0]);
          kB[1][kc] = *(const short8*)(&Ksm[cb][1][(16 + l15) * 128 + c0]);
        }
        __builtin_amdgcn_s_setprio(1);
#pragma unroll
        for (int h2 = 0; h2 < 2; ++h2)
#pragma unroll
          for (int kc = 0; kc < 4; ++kc) {
            s[h2][2] = MFMA32(kB[0][kc], qf[h2][kc], s[h2][2]);
            s[h2][3] = MFMA32(kB[1][kc], qf[h2][kc], s[h2][3]);
          }
        __builtin_amdgcn_s_setprio(0);
      }

      // ---- tail mask in RAW score units ----
      const int kvA = t * 64;
      if (kvA + 64 > Lv) {
#pragma unroll
        for (int h2 = 0; h2 < 2; ++h2)
#pragma unroll
          for (int kb = 0; kb < 4; ++kb)
#pragma unroll
            for (int r = 0; r < 4; ++r) {
              const int ki = kvA + kb * 16 + quad * 4 + r;
              if (ki >= Lv) s[h2][kb][r] = NEGINF;
            }
      }

      // ---- one softmax pass over 64 keys (defer-max, THR = 62 raw = 2^8) ----
      float al[2];
      short8 pfA[2], pfB[2];
#pragma unroll
      for (int h2 = 0; h2 < 2; ++h2) {
        float m0 = fmaxf(fmaxf(s[h2][0][0], s[h2][0][1]), fmaxf(s[h2][0][2], s[h2][0][3]));
        float m1 = fmaxf(fmaxf(s[h2][1][0], s[h2][1][1]), fmaxf(s[h2][1][2], s[h2][1][3]));
        float m2 = fmaxf(fmaxf(s[h2][2][0], s[h2][2][1]), fmaxf(s[h2][2][2], s[h2][2][3]));
        float m3 = fmaxf(fmaxf(s[h2][3][0], s[h2][3][1]), fmaxf(s[h2][3][2], s[h2][3][3]));
        float mx = fmaxf(fmaxf(m0, m1), fmaxf(m2, m3));
        mx = fmaxf(mx, __shfl_xor(mx, 16, 64));
        mx = fmaxf(mx, __shfl_xor(mx, 32, 64));
        const float nm = (mx - run_m[h2] > 62.0f) ? mx : run_m[h2];
        al[h2] = EXP2F((run_m[h2] - nm) * scale2);
        run_m[h2] = nm;
        const float nmc = -nm * scale2;
        float p[4][4], psum = 0.f;
#pragma unroll
        for (int kb = 0; kb < 4; ++kb)
#pragma unroll
          for (int r = 0; r < 4; ++r) {
            p[kb][r] = EXP2F(__builtin_fmaf(s[h2][kb][r], scale2, nmc));
            psum += p[kb][r];
          }
        run_l[h2] = __builtin_fmaf(run_l[h2], al[h2], psum);
        union { short8 s8; unsigned u[4]; } pa, pb;
        pa.u[0] = cvtpk_bf16(p[0][0], p[0][1]);
        pa.u[1] = cvtpk_bf16(p[0][2], p[0][3]);
        pa.u[2] = cvtpk_bf16(p[1][0], p[1][1]);
        pa.u[3] = cvtpk_bf16(p[1][2], p[1][3]);
        pb.u[0] = cvtpk_bf16(p[2][0], p[2][1]);
        pb.u[1] = cvtpk_bf16(p[2][2], p[2][3]);
        pb.u[2] = cvtpk_bf16(p[3][0], p[3][1]);
        pb.u[3] = cvtpk_bf16(p[3][2], p[3][3]);
        pfA[h2] = pa.s8;
        pfB[h2] = pb.s8;
      }
      if (t != 0 && __ballot((al[0] < 1.0f) || (al[1] < 1.0f))) {
#pragma unroll
        for (int h2 = 0; h2 < 2; ++h2)
#pragma unroll
          for (int dt = 0; dt < 8; ++dt)
#pragma unroll
            for (int r = 0; r < 4; ++r) accv[h2][dt][r] *= al[h2];
      }

      // ---- PV: both 32-key halves ----
      __builtin_amdgcn_s_setprio(1);
#pragma unroll
      for (int dt = 0; dt < 8; ++dt) {
        const int vo = (dt * 16 + l15) * 32 + ((quad ^ vxor) * 8);
        short8 vfA = *(const short8*)(&Vsm[cb][0][vo]);
        short8 vfB = *(const short8*)(&Vsm[cb][1][vo]);
        accv[0][dt] = MFMA32(vfA, pfA[0], accv[0][dt]);
        accv[1][dt] = MFMA32(vfA, pfA[1], accv[1][dt]);
        accv[0][dt] = MFMA32(vfB, pfB[0], accv[0][dt]);
        accv[1][dt] = MFMA32(vfB, pfB[1], accv[1][dt]);
      }
      __builtin_amdgcn_s_setprio(0);
      __syncthreads();
    }
  };

  // ---- img phase ----
  const u16* Kb_i = Ki + (size_t)(b * 288) * 2048 + h * 128;
  const u16* Vb_i = Vi + ((size_t)(b * 16 + h) * 128) * 288;
  phase(Kb_i, Vb_i, 257, 288);
#pragma unroll
  for (int h2 = 0; h2 < 2; ++h2) {
    float a = run_l[h2] + __shfl_xor(run_l[h2], 16, 64);
    float lt = a + __shfl_xor(a, 32, 64);
    float inv = 1.0f / lt;
#pragma unroll
    for (int dt = 0; dt < 8; ++dt) {
      u16x4 w2 = { f2bf(accv[h2][dt][0] * inv), f2bf(accv[h2][dt][1] * inv),
                   f2bf(accv[h2][dt][2] * inv), f2bf(accv[h2][dt][3] * inv) };
      oimg[h2][dt] = w2;
    }
  }
  // ---- txt phase ----
  const u16* Kb_t = Kt + (size_t)(b * 512) * 2048 + h * 128;
  const u16* Vb_t = Vt + ((size_t)(b * 16 + h) * 128) * 512;
  phase(Kb_t, Vb_t, lens[b], 512);
#pragma unroll
  for (int h2 = 0; h2 < 2; ++h2) {
    float a = run_l[h2] + __shfl_xor(run_l[h2], 16, 64);
    float lt = a + __shfl_xor(a, 32, 64);
    float inv = 1.0f / lt;
    u16* ob = out + ((size_t)(b * 4096 + qbase + h2 * 16 + l15)) * 2048 + h * 128 + quad * 4;
#pragma unroll
    for (int dt = 0; dt < 8; ++dt) {
      u16x4 w2 = { f2bf(bf2f(oimg[h2][dt][0]) + accv[h2][dt][0] * inv),
                   f2bf(bf2f(oimg[h2][dt][1]) + accv[h2][dt][1] * inv),
                   f2bf(bf2f(oimg[h2][dt][2]) + accv[h2][dt][2] * inv),
                   f2bf(bf2f(oimg[h2][dt][3]) + accv[h2][dt][3] * inv) };
      *(u16x4*)(ob + dt * 16) = w2;
    }
  }
}

extern "C" void kernel_launch(void* const* d_in, const int* in_sizes, int n_in,
                              void* d_out, int out_size, void* d_ws, size_t ws_size,
                              hipStream_t stream) {
  const float* x   = (const float*)d_in[0];
  const float* ctx = (const float*)d_in[1];
  const int* lens  = (const int*)d_in[2];
  const float* Wq  = (const float*)d_in[3];
  const float* bq  = (const float*)d_in[4];
  const float* gq  = (const float*)d_in[5];
  const float* Wk  = (const float*)d_in[6];
  const float* bk  = (const float*)d_in[7];
  const float* gk  = (const float*)d_in[8];
  const float* Wv  = (const float*)d_in[9];
  const float* bv  = (const float*)d_in[10];
  const float* Wki = (const float*)d_in[11];
  const float* bki = (const float*)d_in[12];
  const float* gki = (const float*)d_in[13];
  const float* Wvi = (const float*)d_in[14];
  const float* bvi = (const float*)d_in[15];
  const float* Wo  = (const float*)d_in[16];
  const float* bo  = (const float*)d_in[17];
  float* out = (float*)d_out;

  char* p = (char*)d_ws;
  u16* x_bf   = (u16*)p; p += (size_t)8192 * 2048 * 2;     // reused as attn_out
  u16* ctx_bf = (u16*)p; p += (size_t)2 * 769 * 2048 * 2;
  u16* Wt     = (u16*)p; p += (size_t)6 * 2048 * 2048 * 2;
  u16* Qb     = (u16*)p; p += (size_t)8192 * 2048 * 2;
  u16* Ktxt   = (u16*)p; p += (size_t)2 * 512 * 2048 * 2;
  u16* Vtt    = (u16*)p; p += (size_t)2 * 16 * 128 * 512 * 2;
  u16* Kimg   = (u16*)p; p += (size_t)2 * 288 * 2048 * 2;
  u16* Vti    = (u16*)p; p += (size_t)2 * 16 * 128 * 288 * 2;
  u16* attn_o = x_bf;

  cast_bf16_k<<<16384, 256, 0, stream>>>(x, x_bf, 8192 * 2048 / 4);
  cast_bf16_k<<<3076, 256, 0, stream>>>(ctx, ctx_bf, 2 * 769 * 2048 / 4);
  transw_k<<<dim3(32, 32, 6), 256, 0, stream>>>(Wq, Wk, Wv, Wki, Wvi, Wo, Wt);

  // Q projection: 8192x2048x2048 -> bf16
  gemm256_k<<<dim3(32, 8), 512, 0, stream>>>(x_bf, Wt + 0ull * 4194304, bq, Qb, 0);

  GemmJobs jc = {};
  for (int b = 0; b < 2; ++b) {
    const u16* txtA = ctx_bf + (size_t)(b * 769 + 257) * 2048;
    const u16* imgA = ctx_bf + (size_t)(b * 769) * 2048;
    jc.j[0 + b] = { txtA, Wt + 1ull * 4194304, bk,  Ktxt + (size_t)b * 512 * 2048, 512, 0, 2048 };
    jc.j[2 + b] = { txtA, Wt + 2ull * 4194304, bv,  Vtt  + (size_t)b * 2048 * 512, 512, 1, 512 };
    jc.j[4 + b] = { imgA, Wt + 3ull * 4194304, bki, Kimg + (size_t)b * 288 * 2048, 257, 0, 2048 };
    jc.j[6 + b] = { imgA, Wt + 4ull * 4194304, bvi, Vti  + (size_t)b * 2048 * 288, 257, 1, 288 };
  }
  gemm_k<<<dim3(4, 16, 8), 256, 0, stream>>>(jc);

  rmsnorm_k<<<8192, 256, 0, stream>>>(Qb, gq);
  rmsnorm_k<<<1024, 256, 0, stream>>>(Ktxt, gk);
  rmsnorm_k<<<576, 256, 0, stream>>>(Kimg, gki);

  attn_k<<<dim3(16, 16, 2), 512, 0, stream>>>(Qb, Ktxt, Vtt, Kimg, Vti, lens, attn_o);

  // output projection: 8192x2048x2048 -> fp32
  gemm256_k<<<dim3(32, 8), 512, 0, stream>>>(attn_o, Wt + 5ull * 4194304, bo, out, 1);
}